// Round 14
// baseline (518.204 us; speedup 1.0000x reference)
//
#include <hip/hip_runtime.h>

typedef __attribute__((ext_vector_type(4))) float f32x4;
typedef __attribute__((ext_vector_type(8))) short short8;
typedef unsigned short u16;
typedef unsigned int u32;

__device__ __forceinline__ u16 f2bf(float f){
  u32 x = __float_as_uint(f);
  u32 r = x + 0x7fffu + ((x >> 16) & 1u);
  return (u16)(r >> 16);
}
__device__ __forceinline__ float bf2f32(u32 u){ return __uint_as_float(u << 16); }

__device__ __forceinline__ void gld_lds16(const u16* g, u16* l){
  __builtin_amdgcn_global_load_lds((const __attribute__((address_space(1))) void*)g,
                                   (__attribute__((address_space(3))) void*)l, 16, 0, 0);
}

__device__ __forceinline__ f32x4 mfma16(short8 a, short8 b, f32x4 c){
  return __builtin_amdgcn_mfma_f32_16x16x32_bf16(a, b, c, 0, 0, 0);
}

__device__ __forceinline__ float sigf(float x){
  return __builtin_amdgcn_rcpf(1.0f + __expf(-x));
}
__device__ __forceinline__ float tanhf_(float x){
  float e = __expf(2.0f * x);
  return 1.0f - 2.0f * __builtin_amdgcn_rcpf(e + 1.0f);
}

// ---------------- fused cast f32 -> bf16 (emb, W_hh, W_int, W_out) ----------------
__global__ __launch_bounds__(256) void k_castall(const float* __restrict__ s0, const float* __restrict__ s1,
                          const float* __restrict__ s2, const float* __restrict__ s3,
                          u16* __restrict__ d0, u16* __restrict__ d1, u16* __restrict__ d2,
                          u16* __restrict__ d3)
{
  int i = blockIdx.x * 256 + threadIdx.x;   // float4 index, total 3538944
  const float* s; u16* d; int off;
  if (i < 1572864)      { s = s0; d = d0; off = i; }
  else if (i < 1769472) { s = s1; d = d1; off = i - 1572864; }
  else if (i < 2949120) { s = s2; d = d2; off = i - 1769472; }
  else                  { s = s3; d = d3; off = i - 2949120; }
  float4 v = ((const float4*)s)[off];
  ushort4 o; o.x=f2bf(v.x); o.y=f2bf(v.y); o.z=f2bf(v.z); o.w=f2bf(v.w);
  ((ushort4*)d)[off] = o;
}

// ---------------- W_ih permute-cast: dest row n' = d*512 + dim*4 + gate ----------------
__global__ __launch_bounds__(192) void k_permw(const float* __restrict__ wih, u16* __restrict__ dst)
{
  int np = blockIdx.x;            // dest row 0..6143
  int d = np >> 9, r = np & 511;
  int src = d*512 + (r & 3)*128 + (r >> 2);
  float4 v = ((const float4*)(wih + (size_t)src*768))[threadIdx.x];
  ushort4 o; o.x=f2bf(v.x); o.y=f2bf(v.y); o.z=f2bf(v.z); o.w=f2bf(v.w);
  ((ushort4*)(dst + (size_t)np*768))[threadIdx.x] = o;
}

// -------- persistent pipelined GEMM: BM=256, BN=192, BK=64, TPW tiles/WG --------------
// R14: ONE barrier per K-tile (A 2-buf / B 3-buf make intra-tile staging race-free:
// STAGE(tt+1)/STAGE(tt+2) never touch the buffer being read; barrier_tt guarantees all
// waves finished tile tt-1's reads before its buffers are overwritten). ds_reads are
// software-pipelined one phase ahead so LDS latency hides under the MFMA bursts
// (compiler emits counted lgkmcnt). Counted vmcnt(3) - never drains mid-stream.
// MODE 0: +b_ih+b_hh perm-gathered, bf16. MODE 1: +bias gelu bf16. MODE 2: split-K
// grid halves, f32 to C/C2.
template<int MODE, int TPW>
__global__ __launch_bounds__(512) void k_gemmp(
    const u16* __restrict__ A, const u16* __restrict__ B,
    void* __restrict__ C, void* __restrict__ C2,
    const float* __restrict__ bias1, const float* __restrict__ bias2,
    int M, int N, int K, int lda)
{
  __shared__ __align__(16) u16 lA[2][256*64];
  __shared__ __align__(16) u16 lB[3][192*64];
  int nwg = gridDim.x;
  int bid = blockIdx.x;
  int half = 0;
  if (MODE == 2){
    int h2 = nwg >> 1;
    half = (bid >= h2) ? 1 : 0;
    bid -= half ? h2 : 0;
    nwg = h2;
  }
  int koff = half * K;
  int q = nwg >> 3;
  int swz = (bid & 7) * q + (bid >> 3);   // XCD swizzle (nwg % 8 == 0)
  int nbng = N / (192 * TPW);
  int bm = swz / nbng, bng = swz % nbng;  // XCD chunk shares bm cohort (A in L2)
  int tid = threadIdx.x, lane = tid & 63;
  int wv = tid >> 6;
  int wm = wv & 1, wn = wv >> 1;          // wave tile: rows wm*128, cols wn*48
  int l15 = lane & 15, lhi = lane >> 4;
  const u16* Ag = A + (size_t)(bm << 8) * lda + koff;
  const u16* Bg0 = B + (size_t)(bng * TPW) * 192 * lda + koff;
  size_t bstep = (size_t)192 * lda;

  int srA[4], slA[4];
  #pragma unroll
  for (int i = 0; i < 4; ++i){
    int c = i*512 + tid;                  // A: 2048 chunks of 16B
    srA[i] = c >> 3;
    slA[i] = (((c & 7) ^ (srA[i] & 7)) << 3);
  }
  int srB[3], slB[3];
  #pragma unroll
  for (int i = 0; i < 3; ++i){
    int c = i*512 + tid;                  // B: 1536 chunks
    srB[i] = c >> 3;
    slB[i] = (((c & 7) ^ (srB[i] & 7)) << 3);
  }
  int axr = l15 & 7;
  int aoff0 = (wm*128 + l15)*64 + ((lhi    ) ^ axr)*8;
  int aoff1 = (wm*128 + l15)*64 + ((lhi + 4) ^ axr)*8;
  int boff0 = (wn*48  + l15)*64 + ((lhi    ) ^ axr)*8;
  int boff1 = (wn*48  + l15)*64 + ((lhi + 4) ^ axr)*8;

  f32x4 acc[8][3];
  #pragma unroll
  for (int i = 0; i < 8; ++i)
    #pragma unroll
    for (int j = 0; j < 3; ++j)
      acc[i][j] = (f32x4){0.f,0.f,0.f,0.f};

  int NT = K >> 6;
  int TOT = NT * TPW;

#define STAGE_A(SS)                                                            \
  { int ss_ = (SS); int ko = (ss_ % NT) << 6; u16* dA = lA[ss_ & 1];           \
    _Pragma("unroll")                                                          \
    for (int i = 0; i < 4; ++i)                                                \
      gld_lds16(Ag + (size_t)srA[i]*lda + ko + slA[i], &dA[(i*512+tid)*8]); }
#define STAGE_B(SS)                                                            \
  { int ss_ = (SS); int ko = (ss_ % NT) << 6;                                  \
    const u16* Bb = Bg0 + (size_t)(ss_ / NT) * bstep;                          \
    u16* dB = lB[ss_ % 3];                                                     \
    _Pragma("unroll")                                                          \
    for (int i = 0; i < 3; ++i)                                                \
      gld_lds16(Bb + (size_t)srB[i]*lda + ko + slB[i], &dB[(i*512+tid)*8]); }

#define RD_AF(n0,n1,n2,n3, P)                                                  \
  n0 = *(const short8*)&sA[aoff0 + (2*(P)  )*1024];                            \
  n1 = *(const short8*)&sA[aoff1 + (2*(P)  )*1024];                            \
  n2 = *(const short8*)&sA[aoff0 + (2*(P)+1)*1024];                            \
  n3 = *(const short8*)&sA[aoff1 + (2*(P)+1)*1024];

#define MFMA_B(P, m0,m1,m2,m3)                                                 \
  __builtin_amdgcn_s_setprio(1);                                               \
  _Pragma("unroll")                                                            \
  for (int ni = 0; ni < 3; ++ni){                                              \
    acc[2*(P)  ][ni] = mfma16(m0, bf[ni][0], acc[2*(P)  ][ni]);                \
    acc[2*(P)  ][ni] = mfma16(m1, bf[ni][1], acc[2*(P)  ][ni]);                \
    acc[2*(P)+1][ni] = mfma16(m2, bf[ni][0], acc[2*(P)+1][ni]);                \
    acc[2*(P)+1][ni] = mfma16(m3, bf[ni][1], acc[2*(P)+1][ni]);                \
  }                                                                            \
  __builtin_amdgcn_s_setprio(0);

  STAGE_A(0)
  STAGE_B(0)
  STAGE_B(1)
  asm volatile("s_waitcnt vmcnt(3)" ::: "memory");
  __builtin_amdgcn_s_barrier();

  int kt = 0, tile = 0;
  for (int tt = 0; tt < TOT; ++tt){
    const u16* sA = lA[tt & 1];
    const u16* sB = lB[tt % 3];
    short8 bf[3][2];
    #pragma unroll
    for (int ni = 0; ni < 3; ++ni){
      bf[ni][0] = *(const short8*)&sB[boff0 + ni*1024];
      bf[ni][1] = *(const short8*)&sB[boff1 + ni*1024];
    }
    short8 x0, x1, x2, x3, y0, y1, y2, y3;
    RD_AF(x0,x1,x2,x3, 0)
    if (tt + 1 < TOT){ STAGE_A(tt+1) }
    if (tt + 2 < TOT){ STAGE_B(tt+2) }
    // phase 0: prefetch f1, compute f0
    RD_AF(y0,y1,y2,y3, 1)
    MFMA_B(0, x0,x1,x2,x3)
    // phase 1: prefetch f2, compute f1
    RD_AF(x0,x1,x2,x3, 2)
    MFMA_B(1, y0,y1,y2,y3)
    // phase 2: prefetch f3, compute f2
    RD_AF(y0,y1,y2,y3, 3)
    MFMA_B(2, x0,x1,x2,x3)
    // phase 3: compute f3
    MFMA_B(3, y0,y1,y2,y3)

    if (tt + 2 < TOT){
      asm volatile("s_waitcnt vmcnt(3)" ::: "memory");   // A/B(tt+1) landed; B(tt+2) in flight
    } else if (tt + 1 < TOT){
      asm volatile("s_waitcnt vmcnt(0)" ::: "memory");   // tail
    }
    asm volatile("s_barrier" ::: "memory");

    if (kt == NT - 1){
      // tile epilogue: drain acc -> C, reset; stores retire under next tile's compute
      int bnbase = (bng * TPW + tile) * 192;
      #pragma unroll
      for (int ni = 0; ni < 3; ++ni){
        int n = bnbase + wn*48 + ni*16 + l15;
        float bs;
        if (MODE == 0){
          int d = n >> 9, r = n & 511;
          int src = d*512 + (r & 3)*128 + (r >> 2);
          bs = bias1[src] + bias2[src];
        } else {
          bs = bias1[n];
        }
        #pragma unroll
        for (int mi = 0; mi < 8; ++mi){
          #pragma unroll
          for (int r = 0; r < 4; ++r){
            int m = (bm << 8) + wm*128 + mi*16 + lhi*4 + r;
            float v = acc[mi][ni][r];
            if (MODE == 2){
              if (!half) v += bs;
              ((float*)(half ? C2 : C))[(size_t)m * N + n] = v;
            } else {
              v += bs;
              if (MODE == 1)
                v = 0.5f * v * (1.0f + erff(v * 0.70710678118f));
              ((u16*)C)[(size_t)m * N + n] = f2bf(v);
            }
            acc[mi][ni][r] = 0.f;
          }
        }
      }
      ++tile; kt = 0;
    } else {
      ++kt;
    }
  }
#undef STAGE_A
#undef STAGE_B
#undef RD_AF
#undef MFMA_B
}

// ---------------- LSTM scan: 48 WGs (dir x 4 batch-groups), 512 threads ----------------
__global__ __launch_bounds__(512) void k_scan(const u16* __restrict__ whh, const u16* __restrict__ xp,
                       u16* __restrict__ cat)
{
  __shared__ __align__(16) u16 hb[2][4*144];   // h[batch][dim], rows padded to 144 u16
  int bid = blockIdx.x;
  int d = bid >> 2, bg = bid & 3;
  int tid = threadIdx.x, lane = tid & 63, w = tid >> 6;
  int l15 = lane & 15, lhi = lane >> 4;

  u16* hbf = (u16*)hb;
  for (int i = tid; i < 2*4*144; i += 512) hbf[i] = 0;

  short8 wf[4][4];
  #pragma unroll
  for (int g = 0; g < 4; ++g)
    #pragma unroll
    for (int kk = 0; kk < 4; ++kk)
      wf[g][kk] = *(const short8*)(whh + ((size_t)d*512 + g*128 + w*16 + l15)*128 + kk*32 + lhi*8);

  int b = bg*4 + lhi;
  int dim = w*16 + l15;
  bool fwd = (d < 6);
  const u16* zbase = xp + (size_t)b*512*6144 + d*512 + dim*4;  // + s*6144

  ushort4 Z[4];
  #pragma unroll
  for (int j = 0; j < 4; ++j){
    int s = fwd ? j : 511 - j;
    Z[j] = *(const ushort4*)(zbase + (size_t)s*6144);
  }

  f32x4 a0={0.f,0.f,0.f,0.f}, a1=a0, a2=a0, a3=a0;
  float cr = 0.f;
  int head = fwd ? d : d - 6;
  int posoff = fwd ? 0 : 128;
  size_t catlane = (size_t)b*512*1536 + head*256 + posoff + dim;
  int catoff = fwd ? 0 : 511*1536;
  int catstep = fwd ? 1536 : -1536;

  int hrd = (l15 >> 2)*144 + lhi*8;
  int hwr = lhi*144 + dim;

  __syncthreads();

#define SCAN_STEP(T, RB, WB, S)                                                \
  {                                                                            \
    short8 hf0 = *(const short8*)&hb[RB][hrd + 0*32];                          \
    short8 hf1 = *(const short8*)&hb[RB][hrd + 1*32];                          \
    short8 hf2 = *(const short8*)&hb[RB][hrd + 2*32];                          \
    short8 hf3 = *(const short8*)&hb[RB][hrd + 3*32];                          \
    a0[0] = bf2f32((u32)Z[S].x); a1[0] = bf2f32((u32)Z[S].y);                  \
    a2[0] = bf2f32((u32)Z[S].z); a3[0] = bf2f32((u32)Z[S].w);                  \
    int t4 = (T) + 4; if (t4 > 511) t4 = 511;                                  \
    int s4 = fwd ? t4 : 511 - t4;                                              \
    Z[S] = *(const ushort4*)(zbase + (size_t)s4*6144);                         \
    a2 = mfma16(hf0, wf[2][0], a2); a0 = mfma16(hf0, wf[0][0], a0);            \
    a1 = mfma16(hf0, wf[1][0], a1); a3 = mfma16(hf0, wf[3][0], a3);            \
    a2 = mfma16(hf1, wf[2][1], a2); a0 = mfma16(hf1, wf[0][1], a0);            \
    a1 = mfma16(hf1, wf[1][1], a1); a3 = mfma16(hf1, wf[3][1], a3);            \
    a2 = mfma16(hf2, wf[2][2], a2); a0 = mfma16(hf2, wf[0][2], a0);            \
    a1 = mfma16(hf2, wf[1][2], a1); a3 = mfma16(hf2, wf[3][2], a3);            \
    a2 = mfma16(hf3, wf[2][3], a2); a0 = mfma16(hf3, wf[0][3], a0);            \
    a1 = mfma16(hf3, wf[1][3], a1); a3 = mfma16(hf3, wf[3][3], a3);            \
    float tg = tanhf_(a2[0]);                                                  \
    float fi = sigf(a0[0]), ff = sigf(a1[0]), fo = sigf(a3[0]);                \
    cr = ff*cr + fi*tg;                                                        \
    float hv = fo * tanhf_(cr);                                                \
    u32 hp32;                                                                  \
    asm("v_cvt_pk_bf16_f32 %0, %1, %2" : "=v"(hp32) : "v"(hv), "v"(hv));       \
    u16 hp = (u16)hp32;                                                        \
    hb[WB][hwr] = hp;                                                          \
    cat[catlane + catoff] = hp;                                                \
    catoff += catstep;                                                         \
    asm volatile("s_waitcnt lgkmcnt(0)" ::: "memory");                         \
    __builtin_amdgcn_s_barrier();                                              \
  }

  for (int t = 0; t < 512; t += 4){
    SCAN_STEP(t,   0, 1, 0)
    SCAN_STEP(t+1, 1, 0, 1)
    SCAN_STEP(t+2, 0, 1, 2)
    SCAN_STEP(t+3, 1, 0, 3)
  }
#undef SCAN_STEP
}

// ---------------- residual + LayerNorm (sums two split-K partials) ----------------
__global__ __launch_bounds__(256) void k_ln(const float* __restrict__ emb, const float* __restrict__ p0,
                     const float* __restrict__ p1,
                     const float* __restrict__ gamma, const float* __restrict__ beta,
                     float* __restrict__ out)
{
  int row = blockIdx.x, tid = threadIdx.x;
  const float* pe = emb + (size_t)row * 768;
  const float* pa = p0 + (size_t)row * 768;
  const float* pb = p1 + (size_t)row * 768;
  float v0 = pe[tid]     + pa[tid]     + pb[tid];
  float v1 = pe[tid+256] + pa[tid+256] + pb[tid+256];
  float v2 = pe[tid+512] + pa[tid+512] + pb[tid+512];
  float s = v0+v1+v2, s2 = v0*v0+v1*v1+v2*v2;
  #pragma unroll
  for (int o = 32; o > 0; o >>= 1){ s += __shfl_down(s, o); s2 += __shfl_down(s2, o); }
  __shared__ float rs[4], rq[4];
  int wv = tid >> 6;
  if ((tid & 63) == 0){ rs[wv] = s; rq[wv] = s2; }
  __syncthreads();
  s = rs[0]+rs[1]+rs[2]+rs[3];
  s2 = rq[0]+rq[1]+rq[2]+rq[3];
  float mu = s * (1.0f/768.0f);
  float var = s2 * (1.0f/768.0f) - mu*mu;
  float rr = rsqrtf(var + 1e-5f);
  float* po = out + (size_t)row * 768;
  po[tid]     = (v0-mu)*rr*gamma[tid]     + beta[tid];
  po[tid+256] = (v1-mu)*rr*gamma[tid+256] + beta[tid+256];
  po[tid+512] = (v2-mu)*rr*gamma[tid+512] + beta[tid+512];
}

extern "C" void kernel_launch(void* const* d_in, const int* in_sizes, int n_in,
                              void* d_out, int out_size, void* d_ws, size_t ws_size,
                              hipStream_t stream)
{
  const float* emb   = (const float*)d_in[0];
  const float* W_ih  = (const float*)d_in[1];
  const float* W_hh  = (const float*)d_in[2];
  const float* b_ih  = (const float*)d_in[3];
  const float* b_hh  = (const float*)d_in[4];
  const float* W_int = (const float*)d_in[5];
  const float* b_int = (const float*)d_in[6];
  const float* W_out = (const float*)d_in[7];
  const float* b_out = (const float*)d_in[8];
  const float* gamma = (const float*)d_in[9];
  const float* beta  = (const float*)d_in[10];
  float* out = (float*)d_out;

  char* ws = (char*)d_ws;
  u16* embb  = (u16*)(ws + 0);           // 12,582,912
  u16* wihb  = (u16*)(ws + 12582912);    //  9,437,184 (permuted rows)
  u16* whhb  = (u16*)(ws + 22020096);    //  1,572,864
  u16* wintb = (u16*)(ws + 23592960);    //  9,437,184
  u16* woutb = (u16*)(ws + 33030144);    //  4,718,592
  u16* catb  = (u16*)(ws + 37748736);    // 25,165,824 (dead after GEMM1)
  float* proj1=(float*)(ws + 37748736);  // 25,165,824 (overlays catb)
  u16* xp    = (u16*)(ws + 62914560);    // 100,663,296 (dead after scan)
  u16* interb= (u16*)(ws + 62914560);    // 50,331,648 (reuses xp)
  float* proj0=(float*)(ws + 113246208); // 25,165,824 (reuses xp tail)

  hipLaunchKernelGGL(k_castall, dim3(13824), dim3(256), 0, stream,
                     emb, W_hh, W_int, W_out, embb, whhb, wintb, woutb);
  hipLaunchKernelGGL(k_permw, dim3(6144), dim3(192), 0, stream, W_ih, wihb);

  // x-projection: [8192,768] x [6144,768]^T -> xp row-major (gate-interleaved cols)
  hipLaunchKernelGGL((k_gemmp<0,4>), dim3(256), dim3(512), 0, stream,
                     embb, wihb, (void*)xp, nullptr, b_ih, b_hh, 8192, 6144, 768, 768);
  // sequential BiLSTM scan -> cat [16,512,1536] bf16
  hipLaunchKernelGGL(k_scan, dim3(48), dim3(512), 0, stream, whhb, xp, catb);
  // FFN up + gelu: [8192,1536] x [3072,1536]^T -> inter bf16
  hipLaunchKernelGGL((k_gemmp<1,2>), dim3(256), dim3(512), 0, stream,
                     catb, wintb, (void*)interb, nullptr, b_int, nullptr, 8192, 3072, 1536, 1536);
  // FFN down, split-K x2: [8192,3072] x [768,3072]^T -> proj0 (half0) + proj1 (half1)
  hipLaunchKernelGGL((k_gemmp<2,1>), dim3(256), dim3(512), 0, stream,
                     interb, woutb, (void*)proj0, (void*)proj1, b_out, nullptr, 8192, 768, 1536, 3072);
  // residual + LayerNorm
  hipLaunchKernelGGL(k_ln, dim3(8192), dim3(256), 0, stream, emb, proj0, proj1, gamma, beta, out);
}

// Round 15
// 496.367 us; speedup vs baseline: 1.0440x; 1.0440x over previous
//
#include <hip/hip_runtime.h>

typedef __attribute__((ext_vector_type(4))) float f32x4;
typedef __attribute__((ext_vector_type(8))) short short8;
typedef unsigned short u16;
typedef unsigned int u32;

__device__ __forceinline__ u16 f2bf(float f){
  u32 x = __float_as_uint(f);
  u32 r = x + 0x7fffu + ((x >> 16) & 1u);
  return (u16)(r >> 16);
}
__device__ __forceinline__ float bf2f32(u32 u){ return __uint_as_float(u << 16); }

__device__ __forceinline__ void gld_lds16(const u16* g, u16* l){
  __builtin_amdgcn_global_load_lds((const __attribute__((address_space(1))) void*)g,
                                   (__attribute__((address_space(3))) void*)l, 16, 0, 0);
}

__device__ __forceinline__ f32x4 mfma16(short8 a, short8 b, f32x4 c){
  return __builtin_amdgcn_mfma_f32_16x16x32_bf16(a, b, c, 0, 0, 0);
}

__device__ __forceinline__ float sigf(float x){
  return __builtin_amdgcn_rcpf(1.0f + __expf(-x));
}
__device__ __forceinline__ float tanhf_(float x){
  float e = __expf(2.0f * x);
  return 1.0f - 2.0f * __builtin_amdgcn_rcpf(e + 1.0f);
}

// ---------------- fused cast f32 -> bf16 (emb, W_hh, W_int, W_out) ----------------
__global__ __launch_bounds__(256) void k_castall(const float* __restrict__ s0, const float* __restrict__ s1,
                          const float* __restrict__ s2, const float* __restrict__ s3,
                          u16* __restrict__ d0, u16* __restrict__ d1, u16* __restrict__ d2,
                          u16* __restrict__ d3)
{
  int i = blockIdx.x * 256 + threadIdx.x;   // float4 index, total 3538944
  const float* s; u16* d; int off;
  if (i < 1572864)      { s = s0; d = d0; off = i; }
  else if (i < 1769472) { s = s1; d = d1; off = i - 1572864; }
  else if (i < 2949120) { s = s2; d = d2; off = i - 1769472; }
  else                  { s = s3; d = d3; off = i - 2949120; }
  float4 v = ((const float4*)s)[off];
  ushort4 o; o.x=f2bf(v.x); o.y=f2bf(v.y); o.z=f2bf(v.z); o.w=f2bf(v.w);
  ((ushort4*)d)[off] = o;
}

// ---------------- W_ih permute-cast: dest row n' = d*512 + dim*4 + gate ----------------
__global__ __launch_bounds__(192) void k_permw(const float* __restrict__ wih, u16* __restrict__ dst)
{
  int np = blockIdx.x;            // dest row 0..6143
  int d = np >> 9, r = np & 511;
  int src = d*512 + (r & 3)*128 + (r >> 2);
  float4 v = ((const float4*)(wih + (size_t)src*768))[threadIdx.x];
  ushort4 o; o.x=f2bf(v.x); o.y=f2bf(v.y); o.z=f2bf(v.z); o.w=f2bf(v.w);
  ((ushort4*)(dst + (size_t)np*768))[threadIdx.x] = o;
}

// -------- persistent pipelined GEMM: BM=256, BN=192, BK=64, TPW tiles/WG --------------
// R13 structure with ONE change (R15): pre-MFMA barrier removed -> 4 barriers/tile
// (post-MFMA barrier per phase kept: provides lockstep + staging-safety at tile end).
// p0 stages A(tt+1), p1 stages B(tt+2); p3 waits COUNTED vmcnt(3). A 2-buf / B 3-buf.
// MODE 0: +b_ih+b_hh perm-gathered, bf16. MODE 1: +bias gelu bf16. MODE 2: split-K
// grid halves, f32 to C/C2.
template<int MODE, int TPW>
__global__ __launch_bounds__(512) void k_gemmp(
    const u16* __restrict__ A, const u16* __restrict__ B,
    void* __restrict__ C, void* __restrict__ C2,
    const float* __restrict__ bias1, const float* __restrict__ bias2,
    int M, int N, int K, int lda)
{
  __shared__ __align__(16) u16 lA[2][256*64];
  __shared__ __align__(16) u16 lB[3][192*64];
  int nwg = gridDim.x;
  int bid = blockIdx.x;
  int half = 0;
  if (MODE == 2){
    int h2 = nwg >> 1;
    half = (bid >= h2) ? 1 : 0;
    bid -= half ? h2 : 0;
    nwg = h2;
  }
  int koff = half * K;
  int q = nwg >> 3;
  int swz = (bid & 7) * q + (bid >> 3);   // XCD swizzle (nwg % 8 == 0)
  int nbng = N / (192 * TPW);
  int bm = swz / nbng, bng = swz % nbng;  // XCD chunk shares bm cohort (A in L2)
  int tid = threadIdx.x, lane = tid & 63;
  int wv = tid >> 6;
  int wm = wv & 1, wn = wv >> 1;          // wave tile: rows wm*128, cols wn*48
  int l15 = lane & 15, lhi = lane >> 4;
  const u16* Ag = A + (size_t)(bm << 8) * lda + koff;
  const u16* Bg0 = B + (size_t)(bng * TPW) * 192 * lda + koff;
  size_t bstep = (size_t)192 * lda;

  int srA[4], slA[4];
  #pragma unroll
  for (int i = 0; i < 4; ++i){
    int c = i*512 + tid;                  // A: 2048 chunks of 16B
    srA[i] = c >> 3;
    slA[i] = (((c & 7) ^ (srA[i] & 7)) << 3);
  }
  int srB[3], slB[3];
  #pragma unroll
  for (int i = 0; i < 3; ++i){
    int c = i*512 + tid;                  // B: 1536 chunks
    srB[i] = c >> 3;
    slB[i] = (((c & 7) ^ (srB[i] & 7)) << 3);
  }
  int axr = l15 & 7;
  int aoff0 = (wm*128 + l15)*64 + ((lhi    ) ^ axr)*8;
  int aoff1 = (wm*128 + l15)*64 + ((lhi + 4) ^ axr)*8;
  int boff0 = (wn*48  + l15)*64 + ((lhi    ) ^ axr)*8;
  int boff1 = (wn*48  + l15)*64 + ((lhi + 4) ^ axr)*8;

  f32x4 acc[8][3];
  #pragma unroll
  for (int i = 0; i < 8; ++i)
    #pragma unroll
    for (int j = 0; j < 3; ++j)
      acc[i][j] = (f32x4){0.f,0.f,0.f,0.f};

  int NT = K >> 6;
  int TOT = NT * TPW;

#define STAGE_A(SS)                                                            \
  { int ss_ = (SS); int ko = (ss_ % NT) << 6; u16* dA = lA[ss_ & 1];           \
    _Pragma("unroll")                                                          \
    for (int i = 0; i < 4; ++i)                                                \
      gld_lds16(Ag + (size_t)srA[i]*lda + ko + slA[i], &dA[(i*512+tid)*8]); }
#define STAGE_B(SS)                                                            \
  { int ss_ = (SS); int ko = (ss_ % NT) << 6;                                  \
    const u16* Bb = Bg0 + (size_t)(ss_ / NT) * bstep;                          \
    u16* dB = lB[ss_ % 3];                                                     \
    _Pragma("unroll")                                                          \
    for (int i = 0; i < 3; ++i)                                                \
      gld_lds16(Bb + (size_t)srB[i]*lda + ko + slB[i], &dB[(i*512+tid)*8]); }

  STAGE_A(0)
  STAGE_B(0)
  STAGE_B(1)
  asm volatile("s_waitcnt vmcnt(3)" ::: "memory");
  __builtin_amdgcn_s_barrier();

  int kt = 0, tile = 0;
  for (int tt = 0; tt < TOT; ++tt){
    const u16* sA = lA[tt & 1];
    const u16* sB = lB[tt % 3];
    short8 bf[3][2];
    #pragma unroll
    for (int p = 0; p < 4; ++p){
      if (p == 0){
        #pragma unroll
        for (int ni = 0; ni < 3; ++ni){
          bf[ni][0] = *(const short8*)&sB[boff0 + ni*1024];
          bf[ni][1] = *(const short8*)&sB[boff1 + ni*1024];
        }
      }
      short8 a00 = *(const short8*)&sA[aoff0 + (2*p)*1024];
      short8 a01 = *(const short8*)&sA[aoff1 + (2*p)*1024];
      short8 a10 = *(const short8*)&sA[aoff0 + (2*p+1)*1024];
      short8 a11 = *(const short8*)&sA[aoff1 + (2*p+1)*1024];
      if (p == 0 && tt + 1 < TOT){ STAGE_A(tt+1) }
      if (p == 1 && tt + 2 < TOT){ STAGE_B(tt+2) }
      __builtin_amdgcn_s_setprio(1);
      #pragma unroll
      for (int ni = 0; ni < 3; ++ni){
        acc[2*p  ][ni] = mfma16(a00, bf[ni][0], acc[2*p  ][ni]);
        acc[2*p  ][ni] = mfma16(a01, bf[ni][1], acc[2*p  ][ni]);
        acc[2*p+1][ni] = mfma16(a10, bf[ni][0], acc[2*p+1][ni]);
        acc[2*p+1][ni] = mfma16(a11, bf[ni][1], acc[2*p+1][ni]);
      }
      __builtin_amdgcn_s_setprio(0);
      if (p == 3){
        if (tt + 2 < TOT){
          asm volatile("s_waitcnt vmcnt(3)" ::: "memory");   // A/B(tt+1) landed; B(tt+2) in flight
        } else if (tt + 1 < TOT){
          asm volatile("s_waitcnt vmcnt(0)" ::: "memory");   // tail
        }
      }
      asm volatile("s_barrier" ::: "memory");
    }

    if (kt == NT - 1){
      // tile epilogue: drain acc -> C, reset; stores retire under next tile's compute
      int bnbase = (bng * TPW + tile) * 192;
      #pragma unroll
      for (int ni = 0; ni < 3; ++ni){
        int n = bnbase + wn*48 + ni*16 + l15;
        float bs;
        if (MODE == 0){
          int d = n >> 9, r = n & 511;
          int src = d*512 + (r & 3)*128 + (r >> 2);
          bs = bias1[src] + bias2[src];
        } else {
          bs = bias1[n];
        }
        #pragma unroll
        for (int mi = 0; mi < 8; ++mi){
          #pragma unroll
          for (int r = 0; r < 4; ++r){
            int m = (bm << 8) + wm*128 + mi*16 + lhi*4 + r;
            float v = acc[mi][ni][r];
            if (MODE == 2){
              if (!half) v += bs;
              ((float*)(half ? C2 : C))[(size_t)m * N + n] = v;
            } else {
              v += bs;
              if (MODE == 1)
                v = 0.5f * v * (1.0f + erff(v * 0.70710678118f));
              ((u16*)C)[(size_t)m * N + n] = f2bf(v);
            }
            acc[mi][ni][r] = 0.f;
          }
        }
      }
      ++tile; kt = 0;
    } else {
      ++kt;
    }
  }
#undef STAGE_A
#undef STAGE_B
}

// ---------------- LSTM scan: 48 WGs (dir x 4 batch-groups), 512 threads ----------------
__global__ __launch_bounds__(512) void k_scan(const u16* __restrict__ whh, const u16* __restrict__ xp,
                       u16* __restrict__ cat)
{
  __shared__ __align__(16) u16 hb[2][4*144];   // h[batch][dim], rows padded to 144 u16
  int bid = blockIdx.x;
  int d = bid >> 2, bg = bid & 3;
  int tid = threadIdx.x, lane = tid & 63, w = tid >> 6;
  int l15 = lane & 15, lhi = lane >> 4;

  u16* hbf = (u16*)hb;
  for (int i = tid; i < 2*4*144; i += 512) hbf[i] = 0;

  short8 wf[4][4];
  #pragma unroll
  for (int g = 0; g < 4; ++g)
    #pragma unroll
    for (int kk = 0; kk < 4; ++kk)
      wf[g][kk] = *(const short8*)(whh + ((size_t)d*512 + g*128 + w*16 + l15)*128 + kk*32 + lhi*8);

  int b = bg*4 + lhi;
  int dim = w*16 + l15;
  bool fwd = (d < 6);
  const u16* zbase = xp + (size_t)b*512*6144 + d*512 + dim*4;  // + s*6144

  ushort4 Z[4];
  #pragma unroll
  for (int j = 0; j < 4; ++j){
    int s = fwd ? j : 511 - j;
    Z[j] = *(const ushort4*)(zbase + (size_t)s*6144);
  }

  f32x4 a0={0.f,0.f,0.f,0.f}, a1=a0, a2=a0, a3=a0;
  float cr = 0.f;
  int head = fwd ? d : d - 6;
  int posoff = fwd ? 0 : 128;
  size_t catlane = (size_t)b*512*1536 + head*256 + posoff + dim;
  int catoff = fwd ? 0 : 511*1536;
  int catstep = fwd ? 1536 : -1536;

  int hrd = (l15 >> 2)*144 + lhi*8;
  int hwr = lhi*144 + dim;

  __syncthreads();

#define SCAN_STEP(T, RB, WB, S)                                                \
  {                                                                            \
    short8 hf0 = *(const short8*)&hb[RB][hrd + 0*32];                          \
    short8 hf1 = *(const short8*)&hb[RB][hrd + 1*32];                          \
    short8 hf2 = *(const short8*)&hb[RB][hrd + 2*32];                          \
    short8 hf3 = *(const short8*)&hb[RB][hrd + 3*32];                          \
    a0[0] = bf2f32((u32)Z[S].x); a1[0] = bf2f32((u32)Z[S].y);                  \
    a2[0] = bf2f32((u32)Z[S].z); a3[0] = bf2f32((u32)Z[S].w);                  \
    int t4 = (T) + 4; if (t4 > 511) t4 = 511;                                  \
    int s4 = fwd ? t4 : 511 - t4;                                              \
    Z[S] = *(const ushort4*)(zbase + (size_t)s4*6144);                         \
    a2 = mfma16(hf0, wf[2][0], a2); a0 = mfma16(hf0, wf[0][0], a0);            \
    a1 = mfma16(hf0, wf[1][0], a1); a3 = mfma16(hf0, wf[3][0], a3);            \
    a2 = mfma16(hf1, wf[2][1], a2); a0 = mfma16(hf1, wf[0][1], a0);            \
    a1 = mfma16(hf1, wf[1][1], a1); a3 = mfma16(hf1, wf[3][1], a3);            \
    a2 = mfma16(hf2, wf[2][2], a2); a0 = mfma16(hf2, wf[0][2], a0);            \
    a1 = mfma16(hf2, wf[1][2], a1); a3 = mfma16(hf2, wf[3][2], a3);            \
    a2 = mfma16(hf3, wf[2][3], a2); a0 = mfma16(hf3, wf[0][3], a0);            \
    a1 = mfma16(hf3, wf[1][3], a1); a3 = mfma16(hf3, wf[3][3], a3);            \
    float tg = tanhf_(a2[0]);                                                  \
    float fi = sigf(a0[0]), ff = sigf(a1[0]), fo = sigf(a3[0]);                \
    cr = ff*cr + fi*tg;                                                        \
    float hv = fo * tanhf_(cr);                                                \
    u32 hp32;                                                                  \
    asm("v_cvt_pk_bf16_f32 %0, %1, %2" : "=v"(hp32) : "v"(hv), "v"(hv));       \
    u16 hp = (u16)hp32;                                                        \
    hb[WB][hwr] = hp;                                                          \
    cat[catlane + catoff] = hp;                                                \
    catoff += catstep;                                                         \
    asm volatile("s_waitcnt lgkmcnt(0)" ::: "memory");                         \
    __builtin_amdgcn_s_barrier();                                              \
  }

  for (int t = 0; t < 512; t += 4){
    SCAN_STEP(t,   0, 1, 0)
    SCAN_STEP(t+1, 1, 0, 1)
    SCAN_STEP(t+2, 0, 1, 2)
    SCAN_STEP(t+3, 1, 0, 3)
  }
#undef SCAN_STEP
}

// ---------------- residual + LayerNorm (sums two split-K partials) ----------------
__global__ __launch_bounds__(256) void k_ln(const float* __restrict__ emb, const float* __restrict__ p0,
                     const float* __restrict__ p1,
                     const float* __restrict__ gamma, const float* __restrict__ beta,
                     float* __restrict__ out)
{
  int row = blockIdx.x, tid = threadIdx.x;
  const float* pe = emb + (size_t)row * 768;
  const float* pa = p0 + (size_t)row * 768;
  const float* pb = p1 + (size_t)row * 768;
  float v0 = pe[tid]     + pa[tid]     + pb[tid];
  float v1 = pe[tid+256] + pa[tid+256] + pb[tid+256];
  float v2 = pe[tid+512] + pa[tid+512] + pb[tid+512];
  float s = v0+v1+v2, s2 = v0*v0+v1*v1+v2*v2;
  #pragma unroll
  for (int o = 32; o > 0; o >>= 1){ s += __shfl_down(s, o); s2 += __shfl_down(s2, o); }
  __shared__ float rs[4], rq[4];
  int wv = tid >> 6;
  if ((tid & 63) == 0){ rs[wv] = s; rq[wv] = s2; }
  __syncthreads();
  s = rs[0]+rs[1]+rs[2]+rs[3];
  s2 = rq[0]+rq[1]+rq[2]+rq[3];
  float mu = s * (1.0f/768.0f);
  float var = s2 * (1.0f/768.0f) - mu*mu;
  float rr = rsqrtf(var + 1e-5f);
  float* po = out + (size_t)row * 768;
  po[tid]     = (v0-mu)*rr*gamma[tid]     + beta[tid];
  po[tid+256] = (v1-mu)*rr*gamma[tid+256] + beta[tid+256];
  po[tid+512] = (v2-mu)*rr*gamma[tid+512] + beta[tid+512];
}

extern "C" void kernel_launch(void* const* d_in, const int* in_sizes, int n_in,
                              void* d_out, int out_size, void* d_ws, size_t ws_size,
                              hipStream_t stream)
{
  const float* emb   = (const float*)d_in[0];
  const float* W_ih  = (const float*)d_in[1];
  const float* W_hh  = (const float*)d_in[2];
  const float* b_ih  = (const float*)d_in[3];
  const float* b_hh  = (const float*)d_in[4];
  const float* W_int = (const float*)d_in[5];
  const float* b_int = (const float*)d_in[6];
  const float* W_out = (const float*)d_in[7];
  const float* b_out = (const float*)d_in[8];
  const float* gamma = (const float*)d_in[9];
  const float* beta  = (const float*)d_in[10];
  float* out = (float*)d_out;

  char* ws = (char*)d_ws;
  u16* embb  = (u16*)(ws + 0);           // 12,582,912
  u16* wihb  = (u16*)(ws + 12582912);    //  9,437,184 (permuted rows)
  u16* whhb  = (u16*)(ws + 22020096);    //  1,572,864
  u16* wintb = (u16*)(ws + 23592960);    //  9,437,184
  u16* woutb = (u16*)(ws + 33030144);    //  4,718,592
  u16* catb  = (u16*)(ws + 37748736);    // 25,165,824 (dead after GEMM1)
  float* proj1=(float*)(ws + 37748736);  // 25,165,824 (overlays catb)
  u16* xp    = (u16*)(ws + 62914560);    // 100,663,296 (dead after scan)
  u16* interb= (u16*)(ws + 62914560);    // 50,331,648 (reuses xp)
  float* proj0=(float*)(ws + 113246208); // 25,165,824 (reuses xp tail)

  hipLaunchKernelGGL(k_castall, dim3(13824), dim3(256), 0, stream,
                     emb, W_hh, W_int, W_out, embb, whhb, wintb, woutb);
  hipLaunchKernelGGL(k_permw, dim3(6144), dim3(192), 0, stream, W_ih, wihb);

  // x-projection: [8192,768] x [6144,768]^T -> xp row-major (gate-interleaved cols)
  hipLaunchKernelGGL((k_gemmp<0,4>), dim3(256), dim3(512), 0, stream,
                     embb, wihb, (void*)xp, nullptr, b_ih, b_hh, 8192, 6144, 768, 768);
  // sequential BiLSTM scan -> cat [16,512,1536] bf16
  hipLaunchKernelGGL(k_scan, dim3(48), dim3(512), 0, stream, whhb, xp, catb);
  // FFN up + gelu: [8192,1536] x [3072,1536]^T -> inter bf16
  hipLaunchKernelGGL((k_gemmp<1,2>), dim3(256), dim3(512), 0, stream,
                     catb, wintb, (void*)interb, nullptr, b_int, nullptr, 8192, 3072, 1536, 1536);
  // FFN down, split-K x2: [8192,3072] x [768,3072]^T -> proj0 (half0) + proj1 (half1)
  hipLaunchKernelGGL((k_gemmp<2,1>), dim3(256), dim3(512), 0, stream,
                     interb, woutb, (void*)proj0, (void*)proj1, b_out, nullptr, 8192, 768, 1536, 3072);
  // residual + LayerNorm
  hipLaunchKernelGGL(k_ln, dim3(8192), dim3(256), 0, stream, emb, proj0, proj1, gamma, beta, out);
}

// Round 17
// 495.749 us; speedup vs baseline: 1.0453x; 1.0012x over previous
//
#include <hip/hip_runtime.h>

typedef __attribute__((ext_vector_type(4))) float f32x4;
typedef __attribute__((ext_vector_type(8))) short short8;
typedef unsigned short u16;
typedef unsigned int u32;

__device__ __forceinline__ u16 f2bf(float f){
  u32 x = __float_as_uint(f);
  u32 r = x + 0x7fffu + ((x >> 16) & 1u);
  return (u16)(r >> 16);
}
__device__ __forceinline__ float bf2f32(u32 u){ return __uint_as_float(u << 16); }

__device__ __forceinline__ void gld_lds16(const u16* g, u16* l){
  __builtin_amdgcn_global_load_lds((const __attribute__((address_space(1))) void*)g,
                                   (__attribute__((address_space(3))) void*)l, 16, 0, 0);
}

__device__ __forceinline__ f32x4 mfma16(short8 a, short8 b, f32x4 c){
  return __builtin_amdgcn_mfma_f32_16x16x32_bf16(a, b, c, 0, 0, 0);
}

__device__ __forceinline__ float sigf(float x){
  return __builtin_amdgcn_rcpf(1.0f + __expf(-x));
}
__device__ __forceinline__ float tanhf_(float x){
  float e = __expf(2.0f * x);
  return 1.0f - 2.0f * __builtin_amdgcn_rcpf(e + 1.0f);
}

// ---------------- fused cast f32 -> bf16 (emb, W_hh, W_int, W_out) ----------------
__global__ __launch_bounds__(256) void k_castall(const float* __restrict__ s0, const float* __restrict__ s1,
                          const float* __restrict__ s2, const float* __restrict__ s3,
                          u16* __restrict__ d0, u16* __restrict__ d1, u16* __restrict__ d2,
                          u16* __restrict__ d3)
{
  int i = blockIdx.x * 256 + threadIdx.x;   // float4 index, total 3538944
  const float* s; u16* d; int off;
  if (i < 1572864)      { s = s0; d = d0; off = i; }
  else if (i < 1769472) { s = s1; d = d1; off = i - 1572864; }
  else if (i < 2949120) { s = s2; d = d2; off = i - 1769472; }
  else                  { s = s3; d = d3; off = i - 2949120; }
  float4 v = ((const float4*)s)[off];
  ushort4 o; o.x=f2bf(v.x); o.y=f2bf(v.y); o.z=f2bf(v.z); o.w=f2bf(v.w);
  ((ushort4*)d)[off] = o;
}

// ---------------- W_ih permute-cast: dest row n' = d*512 + dim*4 + gate ----------------
__global__ __launch_bounds__(192) void k_permw(const float* __restrict__ wih, u16* __restrict__ dst)
{
  int np = blockIdx.x;            // dest row 0..6143
  int d = np >> 9, r = np & 511;
  int src = d*512 + (r & 3)*128 + (r >> 2);
  float4 v = ((const float4*)(wih + (size_t)src*768))[threadIdx.x];
  ushort4 o; o.x=f2bf(v.x); o.y=f2bf(v.y); o.z=f2bf(v.z); o.w=f2bf(v.w);
  ((ushort4*)(dst + (size_t)np*768))[threadIdx.x] = o;
}

// ---- persistent GEMM, BN=256 wave-128x64 (G0 only): BM=256, BK=64, TPW tiles/WG ----
// Wave tile 128x64 -> FLOP/LDS-byte 42.7 vs 34.9 at 128x48 (LDS-read-bound regime).
// A 2-buf (64KB) + B 2-buf (64KB) = 128KB. R15 4-barrier schedule: per phase
// {ds_read A quadrant | p0: stage A(tt+1), p1: stage B(tt+1) | setprio MFMA |
//  p3: vmcnt(0) (issued ~3 phases earlier - covered) | s_barrier}.
// MODE 0 only: +b_ih+b_hh perm-gathered, bf16 store row-major.
template<int TPW>
__global__ __launch_bounds__(512) void k_gemmq(
    const u16* __restrict__ A, const u16* __restrict__ B,
    u16* __restrict__ C,
    const float* __restrict__ bias1, const float* __restrict__ bias2,
    int M, int N, int K, int lda)
{
  __shared__ __align__(16) u16 lA[2][256*64];
  __shared__ __align__(16) u16 lB[2][256*64];
  int nwg = gridDim.x;
  int bid = blockIdx.x;
  int q = nwg >> 3;
  int swz = (bid & 7) * q + (bid >> 3);   // XCD swizzle
  int nbng = N / (256 * TPW);
  int bm = swz / nbng, bng = swz % nbng;  // XCD chunk shares bm cohort (A in L2)
  int tid = threadIdx.x, lane = tid & 63;
  int wv = tid >> 6;
  int wm = wv & 1, wn = wv >> 1;          // wave tile: rows wm*128, cols wn*64
  int l15 = lane & 15, lhi = lane >> 4;
  const u16* Ag = A + (size_t)(bm << 8) * lda;
  const u16* Bg0 = B + (size_t)(bng * TPW) * 256 * lda;
  size_t bstep = (size_t)256 * lda;

  int srA[4], slA[4];                     // 2048 chunks of 16B (used for A and B)
  #pragma unroll
  for (int i = 0; i < 4; ++i){
    int c = i*512 + tid;
    srA[i] = c >> 3;
    slA[i] = (((c & 7) ^ (srA[i] & 7)) << 3);
  }
  int axr = l15 & 7;
  int aoff0 = (wm*128 + l15)*64 + ((lhi    ) ^ axr)*8;
  int aoff1 = (wm*128 + l15)*64 + ((lhi + 4) ^ axr)*8;
  int boff0 = (wn*64  + l15)*64 + ((lhi    ) ^ axr)*8;
  int boff1 = (wn*64  + l15)*64 + ((lhi + 4) ^ axr)*8;

  f32x4 acc[8][4];
  #pragma unroll
  for (int i = 0; i < 8; ++i)
    #pragma unroll
    for (int j = 0; j < 4; ++j)
      acc[i][j] = (f32x4){0.f,0.f,0.f,0.f};

  int NT = K >> 6;
  int TOT = NT * TPW;

#define STAGE_A(SS)                                                            \
  { int ss_ = (SS); int ko = (ss_ % NT) << 6; u16* dA = lA[ss_ & 1];           \
    _Pragma("unroll")                                                          \
    for (int i = 0; i < 4; ++i)                                                \
      gld_lds16(Ag + (size_t)srA[i]*lda + ko + slA[i], &dA[(i*512+tid)*8]); }
#define STAGE_B(SS)                                                            \
  { int ss_ = (SS); int ko = (ss_ % NT) << 6;                                  \
    const u16* Bb = Bg0 + (size_t)(ss_ / NT) * bstep;                          \
    u16* dB = lB[ss_ & 1];                                                     \
    _Pragma("unroll")                                                          \
    for (int i = 0; i < 4; ++i)                                                \
      gld_lds16(Bb + (size_t)srA[i]*lda + ko + slA[i], &dB[(i*512+tid)*8]); }

  STAGE_A(0)
  STAGE_B(0)
  asm volatile("s_waitcnt vmcnt(0)" ::: "memory");
  __builtin_amdgcn_s_barrier();

  int kt = 0, tile = 0;
  for (int tt = 0; tt < TOT; ++tt){
    const u16* sA = lA[tt & 1];
    const u16* sB = lB[tt & 1];
    short8 bf[4][2];
    #pragma unroll
    for (int p = 0; p < 4; ++p){
      if (p == 0){
        #pragma unroll
        for (int ni = 0; ni < 4; ++ni){
          bf[ni][0] = *(const short8*)&sB[boff0 + ni*1024];
          bf[ni][1] = *(const short8*)&sB[boff1 + ni*1024];
        }
      }
      short8 a00 = *(const short8*)&sA[aoff0 + (2*p)*1024];
      short8 a01 = *(const short8*)&sA[aoff1 + (2*p)*1024];
      short8 a10 = *(const short8*)&sA[aoff0 + (2*p+1)*1024];
      short8 a11 = *(const short8*)&sA[aoff1 + (2*p+1)*1024];
      if (p == 0 && tt + 1 < TOT){ STAGE_A(tt+1) }
      if (p == 1 && tt + 1 < TOT){ STAGE_B(tt+1) }
      __builtin_amdgcn_s_setprio(1);
      #pragma unroll
      for (int ni = 0; ni < 4; ++ni){
        acc[2*p  ][ni] = mfma16(a00, bf[ni][0], acc[2*p  ][ni]);
        acc[2*p  ][ni] = mfma16(a01, bf[ni][1], acc[2*p  ][ni]);
        acc[2*p+1][ni] = mfma16(a10, bf[ni][0], acc[2*p+1][ni]);
        acc[2*p+1][ni] = mfma16(a11, bf[ni][1], acc[2*p+1][ni]);
      }
      __builtin_amdgcn_s_setprio(0);
      if (p == 3 && tt + 1 < TOT){
        asm volatile("s_waitcnt vmcnt(0)" ::: "memory");   // issued ~3 phases ago
      }
      asm volatile("s_barrier" ::: "memory");
    }

    if (kt == NT - 1){
      // tile epilogue: +perm-gathered bias, bf16 store row-major
      int bnbase = (bng * TPW + tile) * 256;
      #pragma unroll
      for (int ni = 0; ni < 4; ++ni){
        int n = bnbase + wn*64 + ni*16 + l15;
        int dd = n >> 9, r9 = n & 511;
        int src = dd*512 + (r9 & 3)*128 + (r9 >> 2);
        float bs = bias1[src] + bias2[src];
        #pragma unroll
        for (int mi = 0; mi < 8; ++mi){
          #pragma unroll
          for (int r = 0; r < 4; ++r){
            int m = (bm << 8) + wm*128 + mi*16 + lhi*4 + r;
            C[(size_t)m * N + n] = f2bf(acc[mi][ni][r] + bs);
            acc[mi][ni][r] = 0.f;
          }
        }
      }
      ++tile; kt = 0;
    } else {
      ++kt;
    }
  }
#undef STAGE_A
#undef STAGE_B
}

// -------- persistent pipelined GEMM (R15, unchanged): BM=256, BN=192, BK=64 ----------
template<int MODE, int TPW>
__global__ __launch_bounds__(512) void k_gemmp(
    const u16* __restrict__ A, const u16* __restrict__ B,
    void* __restrict__ C, void* __restrict__ C2,
    const float* __restrict__ bias1, const float* __restrict__ bias2,
    int M, int N, int K, int lda)
{
  __shared__ __align__(16) u16 lA[2][256*64];
  __shared__ __align__(16) u16 lB[3][192*64];
  int nwg = gridDim.x;
  int bid = blockIdx.x;
  int half = 0;
  if (MODE == 2){
    int h2 = nwg >> 1;
    half = (bid >= h2) ? 1 : 0;
    bid -= half ? h2 : 0;
    nwg = h2;
  }
  int koff = half * K;
  int q = nwg >> 3;
  int swz = (bid & 7) * q + (bid >> 3);
  int nbng = N / (192 * TPW);
  int bm = swz / nbng, bng = swz % nbng;
  int tid = threadIdx.x, lane = tid & 63;
  int wv = tid >> 6;
  int wm = wv & 1, wn = wv >> 1;
  int l15 = lane & 15, lhi = lane >> 4;
  const u16* Ag = A + (size_t)(bm << 8) * lda + koff;
  const u16* Bg0 = B + (size_t)(bng * TPW) * 192 * lda + koff;
  size_t bstep = (size_t)192 * lda;

  int srA[4], slA[4];
  #pragma unroll
  for (int i = 0; i < 4; ++i){
    int c = i*512 + tid;
    srA[i] = c >> 3;
    slA[i] = (((c & 7) ^ (srA[i] & 7)) << 3);
  }
  int srB[3], slB[3];
  #pragma unroll
  for (int i = 0; i < 3; ++i){
    int c = i*512 + tid;
    srB[i] = c >> 3;
    slB[i] = (((c & 7) ^ (srB[i] & 7)) << 3);
  }
  int axr = l15 & 7;
  int aoff0 = (wm*128 + l15)*64 + ((lhi    ) ^ axr)*8;
  int aoff1 = (wm*128 + l15)*64 + ((lhi + 4) ^ axr)*8;
  int boff0 = (wn*48  + l15)*64 + ((lhi    ) ^ axr)*8;
  int boff1 = (wn*48  + l15)*64 + ((lhi + 4) ^ axr)*8;

  f32x4 acc[8][3];
  #pragma unroll
  for (int i = 0; i < 8; ++i)
    #pragma unroll
    for (int j = 0; j < 3; ++j)
      acc[i][j] = (f32x4){0.f,0.f,0.f,0.f};

  int NT = K >> 6;
  int TOT = NT * TPW;

#define STAGE_A(SS)                                                            \
  { int ss_ = (SS); int ko = (ss_ % NT) << 6; u16* dA = lA[ss_ & 1];           \
    _Pragma("unroll")                                                          \
    for (int i = 0; i < 4; ++i)                                                \
      gld_lds16(Ag + (size_t)srA[i]*lda + ko + slA[i], &dA[(i*512+tid)*8]); }
#define STAGE_B(SS)                                                            \
  { int ss_ = (SS); int ko = (ss_ % NT) << 6;                                  \
    const u16* Bb = Bg0 + (size_t)(ss_ / NT) * bstep;                          \
    u16* dB = lB[ss_ % 3];                                                     \
    _Pragma("unroll")                                                          \
    for (int i = 0; i < 3; ++i)                                                \
      gld_lds16(Bb + (size_t)srB[i]*lda + ko + slB[i], &dB[(i*512+tid)*8]); }

  STAGE_A(0)
  STAGE_B(0)
  STAGE_B(1)
  asm volatile("s_waitcnt vmcnt(3)" ::: "memory");
  __builtin_amdgcn_s_barrier();

  int kt = 0, tile = 0;
  for (int tt = 0; tt < TOT; ++tt){
    const u16* sA = lA[tt & 1];
    const u16* sB = lB[tt % 3];
    short8 bf[3][2];
    #pragma unroll
    for (int p = 0; p < 4; ++p){
      if (p == 0){
        #pragma unroll
        for (int ni = 0; ni < 3; ++ni){
          bf[ni][0] = *(const short8*)&sB[boff0 + ni*1024];
          bf[ni][1] = *(const short8*)&sB[boff1 + ni*1024];
        }
      }
      short8 a00 = *(const short8*)&sA[aoff0 + (2*p)*1024];
      short8 a01 = *(const short8*)&sA[aoff1 + (2*p)*1024];
      short8 a10 = *(const short8*)&sA[aoff0 + (2*p+1)*1024];
      short8 a11 = *(const short8*)&sA[aoff1 + (2*p+1)*1024];
      if (p == 0 && tt + 1 < TOT){ STAGE_A(tt+1) }
      if (p == 1 && tt + 2 < TOT){ STAGE_B(tt+2) }
      __builtin_amdgcn_s_setprio(1);
      #pragma unroll
      for (int ni = 0; ni < 3; ++ni){
        acc[2*p  ][ni] = mfma16(a00, bf[ni][0], acc[2*p  ][ni]);
        acc[2*p  ][ni] = mfma16(a01, bf[ni][1], acc[2*p  ][ni]);
        acc[2*p+1][ni] = mfma16(a10, bf[ni][0], acc[2*p+1][ni]);
        acc[2*p+1][ni] = mfma16(a11, bf[ni][1], acc[2*p+1][ni]);
      }
      __builtin_amdgcn_s_setprio(0);
      if (p == 3){
        if (tt + 2 < TOT){
          asm volatile("s_waitcnt vmcnt(3)" ::: "memory");
        } else if (tt + 1 < TOT){
          asm volatile("s_waitcnt vmcnt(0)" ::: "memory");
        }
      }
      asm volatile("s_barrier" ::: "memory");
    }

    if (kt == NT - 1){
      int bnbase = (bng * TPW + tile) * 192;
      #pragma unroll
      for (int ni = 0; ni < 3; ++ni){
        int n = bnbase + wn*48 + ni*16 + l15;
        float bs;
        if (MODE == 0){
          int d = n >> 9, r = n & 511;
          int src = d*512 + (r & 3)*128 + (r >> 2);
          bs = bias1[src] + bias2[src];
        } else {
          bs = bias1[n];
        }
        #pragma unroll
        for (int mi = 0; mi < 8; ++mi){
          #pragma unroll
          for (int r = 0; r < 4; ++r){
            int m = (bm << 8) + wm*128 + mi*16 + lhi*4 + r;
            float v = acc[mi][ni][r];
            if (MODE == 2){
              if (!half) v += bs;
              ((float*)(half ? C2 : C))[(size_t)m * N + n] = v;
            } else {
              v += bs;
              if (MODE == 1)
                v = 0.5f * v * (1.0f + erff(v * 0.70710678118f));
              ((u16*)C)[(size_t)m * N + n] = f2bf(v);
            }
            acc[mi][ni][r] = 0.f;
          }
        }
      }
      ++tile; kt = 0;
    } else {
      ++kt;
    }
  }
#undef STAGE_A
#undef STAGE_B
}

// ---------------- LSTM scan: 48 WGs (dir x 4 batch-groups), 512 threads ----------------
__global__ __launch_bounds__(512) void k_scan(const u16* __restrict__ whh, const u16* __restrict__ xp,
                       u16* __restrict__ cat)
{
  __shared__ __align__(16) u16 hb[2][4*144];   // h[batch][dim], rows padded to 144 u16
  int bid = blockIdx.x;
  int d = bid >> 2, bg = bid & 3;
  int tid = threadIdx.x, lane = tid & 63, w = tid >> 6;
  int l15 = lane & 15, lhi = lane >> 4;

  u16* hbf = (u16*)hb;
  for (int i = tid; i < 2*4*144; i += 512) hbf[i] = 0;

  short8 wf[4][4];
  #pragma unroll
  for (int g = 0; g < 4; ++g)
    #pragma unroll
    for (int kk = 0; kk < 4; ++kk)
      wf[g][kk] = *(const short8*)(whh + ((size_t)d*512 + g*128 + w*16 + l15)*128 + kk*32 + lhi*8);

  int b = bg*4 + lhi;
  int dim = w*16 + l15;
  bool fwd = (d < 6);
  const u16* zbase = xp + (size_t)b*512*6144 + d*512 + dim*4;  // + s*6144

  ushort4 Z[4];
  #pragma unroll
  for (int j = 0; j < 4; ++j){
    int s = fwd ? j : 511 - j;
    Z[j] = *(const ushort4*)(zbase + (size_t)s*6144);
  }

  f32x4 a0={0.f,0.f,0.f,0.f}, a1=a0, a2=a0, a3=a0;
  float cr = 0.f;
  int head = fwd ? d : d - 6;
  int posoff = fwd ? 0 : 128;
  size_t catlane = (size_t)b*512*1536 + head*256 + posoff + dim;
  int catoff = fwd ? 0 : 511*1536;
  int catstep = fwd ? 1536 : -1536;

  int hrd = (l15 >> 2)*144 + lhi*8;
  int hwr = lhi*144 + dim;

  __syncthreads();

#define SCAN_STEP(T, RB, WB, S)                                                \
  {                                                                            \
    short8 hf0 = *(const short8*)&hb[RB][hrd + 0*32];                          \
    short8 hf1 = *(const short8*)&hb[RB][hrd + 1*32];                          \
    short8 hf2 = *(const short8*)&hb[RB][hrd + 2*32];                          \
    short8 hf3 = *(const short8*)&hb[RB][hrd + 3*32];                          \
    a0[0] = bf2f32((u32)Z[S].x); a1[0] = bf2f32((u32)Z[S].y);                  \
    a2[0] = bf2f32((u32)Z[S].z); a3[0] = bf2f32((u32)Z[S].w);                  \
    int t4 = (T) + 4; if (t4 > 511) t4 = 511;                                  \
    int s4 = fwd ? t4 : 511 - t4;                                              \
    Z[S] = *(const ushort4*)(zbase + (size_t)s4*6144);                         \
    a2 = mfma16(hf0, wf[2][0], a2); a0 = mfma16(hf0, wf[0][0], a0);            \
    a1 = mfma16(hf0, wf[1][0], a1); a3 = mfma16(hf0, wf[3][0], a3);            \
    a2 = mfma16(hf1, wf[2][1], a2); a0 = mfma16(hf1, wf[0][1], a0);            \
    a1 = mfma16(hf1, wf[1][1], a1); a3 = mfma16(hf1, wf[3][1], a3);            \
    a2 = mfma16(hf2, wf[2][2], a2); a0 = mfma16(hf2, wf[0][2], a0);            \
    a1 = mfma16(hf2, wf[1][2], a1); a3 = mfma16(hf2, wf[3][2], a3);            \
    a2 = mfma16(hf3, wf[2][3], a2); a0 = mfma16(hf3, wf[0][3], a0);            \
    a1 = mfma16(hf3, wf[1][3], a1); a3 = mfma16(hf3, wf[3][3], a3);            \
    float tg = tanhf_(a2[0]);                                                  \
    float fi = sigf(a0[0]), ff = sigf(a1[0]), fo = sigf(a3[0]);                \
    cr = ff*cr + fi*tg;                                                        \
    float hv = fo * tanhf_(cr);                                                \
    u32 hp32;                                                                  \
    asm("v_cvt_pk_bf16_f32 %0, %1, %2" : "=v"(hp32) : "v"(hv), "v"(hv));       \
    u16 hp = (u16)hp32;                                                        \
    hb[WB][hwr] = hp;                                                          \
    cat[catlane + catoff] = hp;                                                \
    catoff += catstep;                                                         \
    asm volatile("s_waitcnt lgkmcnt(0)" ::: "memory");                         \
    __builtin_amdgcn_s_barrier();                                              \
  }

  for (int t = 0; t < 512; t += 4){
    SCAN_STEP(t,   0, 1, 0)
    SCAN_STEP(t+1, 1, 0, 1)
    SCAN_STEP(t+2, 0, 1, 2)
    SCAN_STEP(t+3, 1, 0, 3)
  }
#undef SCAN_STEP
}

// ---------------- residual + LayerNorm (sums two split-K partials) ----------------
__global__ __launch_bounds__(256) void k_ln(const float* __restrict__ emb, const float* __restrict__ p0,
                     const float* __restrict__ p1,
                     const float* __restrict__ gamma, const float* __restrict__ beta,
                     float* __restrict__ out)
{
  int row = blockIdx.x, tid = threadIdx.x;
  const float* pe = emb + (size_t)row * 768;
  const float* pa = p0 + (size_t)row * 768;
  const float* pb = p1 + (size_t)row * 768;
  float v0 = pe[tid]     + pa[tid]     + pb[tid];
  float v1 = pe[tid+256] + pa[tid+256] + pb[tid+256];
  float v2 = pe[tid+512] + pa[tid+512] + pb[tid+512];
  float s = v0+v1+v2, s2 = v0*v0+v1*v1+v2*v2;
  #pragma unroll
  for (int o = 32; o > 0; o >>= 1){ s += __shfl_down(s, o); s2 += __shfl_down(s2, o); }
  __shared__ float rs[4], rq[4];
  int wv = tid >> 6;
  if ((tid & 63) == 0){ rs[wv] = s; rq[wv] = s2; }
  __syncthreads();
  s = rs[0]+rs[1]+rs[2]+rs[3];
  s2 = rq[0]+rq[1]+rq[2]+rq[3];
  float mu = s * (1.0f/768.0f);
  float var = s2 * (1.0f/768.0f) - mu*mu;
  float rr = rsqrtf(var + 1e-5f);
  float* po = out + (size_t)row * 768;
  po[tid]     = (v0-mu)*rr*gamma[tid]     + beta[tid];
  po[tid+256] = (v1-mu)*rr*gamma[tid+256] + beta[tid+256];
  po[tid+512] = (v2-mu)*rr*gamma[tid+512] + beta[tid+512];
}

extern "C" void kernel_launch(void* const* d_in, const int* in_sizes, int n_in,
                              void* d_out, int out_size, void* d_ws, size_t ws_size,
                              hipStream_t stream)
{
  const float* emb   = (const float*)d_in[0];
  const float* W_ih  = (const float*)d_in[1];
  const float* W_hh  = (const float*)d_in[2];
  const float* b_ih  = (const float*)d_in[3];
  const float* b_hh  = (const float*)d_in[4];
  const float* W_int = (const float*)d_in[5];
  const float* b_int = (const float*)d_in[6];
  const float* W_out = (const float*)d_in[7];
  const float* b_out = (const float*)d_in[8];
  const float* gamma = (const float*)d_in[9];
  const float* beta  = (const float*)d_in[10];
  float* out = (float*)d_out;

  char* ws = (char*)d_ws;
  u16* embb  = (u16*)(ws + 0);           // 12,582,912
  u16* wihb  = (u16*)(ws + 12582912);    //  9,437,184 (permuted rows)
  u16* whhb  = (u16*)(ws + 22020096);    //  1,572,864
  u16* wintb = (u16*)(ws + 23592960);    //  9,437,184
  u16* woutb = (u16*)(ws + 33030144);    //  4,718,592
  u16* catb  = (u16*)(ws + 37748736);    // 25,165,824 (dead after GEMM1)
  float* proj1=(float*)(ws + 37748736);  // 25,165,824 (overlays catb)
  u16* xp    = (u16*)(ws + 62914560);    // 100,663,296 (dead after scan)
  u16* interb= (u16*)(ws + 62914560);    // 50,331,648 (reuses xp)
  float* proj0=(float*)(ws + 113246208); // 25,165,824 (reuses xp tail)

  hipLaunchKernelGGL(k_castall, dim3(13824), dim3(256), 0, stream,
                     emb, W_hh, W_int, W_out, embb, whhb, wintb, woutb);
  hipLaunchKernelGGL(k_permw, dim3(6144), dim3(192), 0, stream, W_ih, wihb);

  // x-projection: [8192,768] x [6144,768]^T -> xp row-major (gate-interleaved cols)
  // BN=256 wave-128x64 variant (LDS-read-bound fix), 32bm x 8bng x TPW3 = 256 WGs
  hipLaunchKernelGGL((k_gemmq<3>), dim3(256), dim3(512), 0, stream,
                     embb, wihb, xp, b_ih, b_hh, 8192, 6144, 768, 768);
  // sequential BiLSTM scan -> cat [16,512,1536] bf16
  hipLaunchKernelGGL(k_scan, dim3(48), dim3(512), 0, stream, whhb, xp, catb);
  // FFN up + gelu: [8192,1536] x [3072,1536]^T -> inter bf16
  hipLaunchKernelGGL((k_gemmp<1,2>), dim3(256), dim3(512), 0, stream,
                     catb, wintb, (void*)interb, nullptr, b_int, nullptr, 8192, 3072, 1536, 1536);
  // FFN down, split-K x2: [8192,3072] x [768,3072]^T -> proj0 (half0) + proj1 (half1)
  hipLaunchKernelGGL((k_gemmp<2,1>), dim3(256), dim3(512), 0, stream,
                     interb, woutb, (void*)proj0, (void*)proj1, b_out, nullptr, 8192, 768, 1536, 3072);
  // residual + LayerNorm
  hipLaunchKernelGGL(k_ln, dim3(8192), dim3(256), 0, stream, emb, proj0, proj1, gamma, beta, out);
}

// Round 18
// 495.733 us; speedup vs baseline: 1.0453x; 1.0000x over previous
//
#include <hip/hip_runtime.h>

typedef __attribute__((ext_vector_type(4))) float f32x4;
typedef __attribute__((ext_vector_type(8))) short short8;
typedef unsigned short u16;
typedef unsigned int u32;

__device__ __forceinline__ u16 f2bf(float f){
  u32 x = __float_as_uint(f);
  u32 r = x + 0x7fffu + ((x >> 16) & 1u);
  return (u16)(r >> 16);
}
__device__ __forceinline__ float bf2f32(u32 u){ return __uint_as_float(u << 16); }

__device__ __forceinline__ void gld_lds16(const u16* g, u16* l){
  __builtin_amdgcn_global_load_lds((const __attribute__((address_space(1))) void*)g,
                                   (__attribute__((address_space(3))) void*)l, 16, 0, 0);
}

__device__ __forceinline__ f32x4 mfma16(short8 a, short8 b, f32x4 c){
  return __builtin_amdgcn_mfma_f32_16x16x32_bf16(a, b, c, 0, 0, 0);
}

__device__ __forceinline__ float sigf(float x){
  return __builtin_amdgcn_rcpf(1.0f + __expf(-x));
}
__device__ __forceinline__ float tanhf_(float x){
  float e = __expf(2.0f * x);
  return 1.0f - 2.0f * __builtin_amdgcn_rcpf(e + 1.0f);
}

// ---------------- fused cast f32 -> bf16 (emb, W_hh, W_int, W_out) ----------------
__global__ __launch_bounds__(256) void k_castall(const float* __restrict__ s0, const float* __restrict__ s1,
                          const float* __restrict__ s2, const float* __restrict__ s3,
                          u16* __restrict__ d0, u16* __restrict__ d1, u16* __restrict__ d2,
                          u16* __restrict__ d3)
{
  int i = blockIdx.x * 256 + threadIdx.x;   // float4 index, total 3538944
  const float* s; u16* d; int off;
  if (i < 1572864)      { s = s0; d = d0; off = i; }
  else if (i < 1769472) { s = s1; d = d1; off = i - 1572864; }
  else if (i < 2949120) { s = s2; d = d2; off = i - 1769472; }
  else                  { s = s3; d = d3; off = i - 2949120; }
  float4 v = ((const float4*)s)[off];
  ushort4 o; o.x=f2bf(v.x); o.y=f2bf(v.y); o.z=f2bf(v.z); o.w=f2bf(v.w);
  ((ushort4*)d)[off] = o;
}

// ---------------- W_ih permute-cast: dest row n' = d*512 + dim*4 + gate ----------------
__global__ __launch_bounds__(192) void k_permw(const float* __restrict__ wih, u16* __restrict__ dst)
{
  int np = blockIdx.x;            // dest row 0..6143
  int d = np >> 9, r = np & 511;
  int src = d*512 + (r & 3)*128 + (r >> 2);
  float4 v = ((const float4*)(wih + (size_t)src*768))[threadIdx.x];
  ushort4 o; o.x=f2bf(v.x); o.y=f2bf(v.y); o.z=f2bf(v.z); o.w=f2bf(v.w);
  ((ushort4*)(dst + (size_t)np*768))[threadIdx.x] = o;
}

// ---- persistent GEMM, BN=256 wave-128x64 (G0 only): BM=256, BK=64, TPW tiles/WG ----
template<int TPW>
__global__ __launch_bounds__(512) void k_gemmq(
    const u16* __restrict__ A, const u16* __restrict__ B,
    u16* __restrict__ C,
    const float* __restrict__ bias1, const float* __restrict__ bias2,
    int M, int N, int K, int lda)
{
  __shared__ __align__(16) u16 lA[2][256*64];
  __shared__ __align__(16) u16 lB[2][256*64];
  int nwg = gridDim.x;
  int bid = blockIdx.x;
  int q = nwg >> 3;
  int swz = (bid & 7) * q + (bid >> 3);   // XCD swizzle
  int nbng = N / (256 * TPW);
  int bm = swz / nbng, bng = swz % nbng;  // XCD chunk shares bm cohort (A in L2)
  int tid = threadIdx.x, lane = tid & 63;
  int wv = tid >> 6;
  int wm = wv & 1, wn = wv >> 1;          // wave tile: rows wm*128, cols wn*64
  int l15 = lane & 15, lhi = lane >> 4;
  const u16* Ag = A + (size_t)(bm << 8) * lda;
  const u16* Bg0 = B + (size_t)(bng * TPW) * 256 * lda;
  size_t bstep = (size_t)256 * lda;

  int srA[4], slA[4];                     // 2048 chunks of 16B (used for A and B)
  #pragma unroll
  for (int i = 0; i < 4; ++i){
    int c = i*512 + tid;
    srA[i] = c >> 3;
    slA[i] = (((c & 7) ^ (srA[i] & 7)) << 3);
  }
  int axr = l15 & 7;
  int aoff0 = (wm*128 + l15)*64 + ((lhi    ) ^ axr)*8;
  int aoff1 = (wm*128 + l15)*64 + ((lhi + 4) ^ axr)*8;
  int boff0 = (wn*64  + l15)*64 + ((lhi    ) ^ axr)*8;
  int boff1 = (wn*64  + l15)*64 + ((lhi + 4) ^ axr)*8;

  f32x4 acc[8][4];
  #pragma unroll
  for (int i = 0; i < 8; ++i)
    #pragma unroll
    for (int j = 0; j < 4; ++j)
      acc[i][j] = (f32x4){0.f,0.f,0.f,0.f};

  int NT = K >> 6;
  int TOT = NT * TPW;

#define STAGE_A(SS)                                                            \
  { int ss_ = (SS); int ko = (ss_ % NT) << 6; u16* dA = lA[ss_ & 1];           \
    _Pragma("unroll")                                                          \
    for (int i = 0; i < 4; ++i)                                                \
      gld_lds16(Ag + (size_t)srA[i]*lda + ko + slA[i], &dA[(i*512+tid)*8]); }
#define STAGE_B(SS)                                                            \
  { int ss_ = (SS); int ko = (ss_ % NT) << 6;                                  \
    const u16* Bb = Bg0 + (size_t)(ss_ / NT) * bstep;                          \
    u16* dB = lB[ss_ & 1];                                                     \
    _Pragma("unroll")                                                          \
    for (int i = 0; i < 4; ++i)                                                \
      gld_lds16(Bb + (size_t)srA[i]*lda + ko + slA[i], &dB[(i*512+tid)*8]); }

  STAGE_A(0)
  STAGE_B(0)
  asm volatile("s_waitcnt vmcnt(0)" ::: "memory");
  __builtin_amdgcn_s_barrier();

  int kt = 0, tile = 0;
  for (int tt = 0; tt < TOT; ++tt){
    const u16* sA = lA[tt & 1];
    const u16* sB = lB[tt & 1];
    short8 bf[4][2];
    #pragma unroll
    for (int p = 0; p < 4; ++p){
      if (p == 0){
        #pragma unroll
        for (int ni = 0; ni < 4; ++ni){
          bf[ni][0] = *(const short8*)&sB[boff0 + ni*1024];
          bf[ni][1] = *(const short8*)&sB[boff1 + ni*1024];
        }
      }
      short8 a00 = *(const short8*)&sA[aoff0 + (2*p)*1024];
      short8 a01 = *(const short8*)&sA[aoff1 + (2*p)*1024];
      short8 a10 = *(const short8*)&sA[aoff0 + (2*p+1)*1024];
      short8 a11 = *(const short8*)&sA[aoff1 + (2*p+1)*1024];
      if (p == 0 && tt + 1 < TOT){ STAGE_A(tt+1) }
      if (p == 1 && tt + 1 < TOT){ STAGE_B(tt+1) }
      __builtin_amdgcn_s_setprio(1);
      #pragma unroll
      for (int ni = 0; ni < 4; ++ni){
        acc[2*p  ][ni] = mfma16(a00, bf[ni][0], acc[2*p  ][ni]);
        acc[2*p  ][ni] = mfma16(a01, bf[ni][1], acc[2*p  ][ni]);
        acc[2*p+1][ni] = mfma16(a10, bf[ni][0], acc[2*p+1][ni]);
        acc[2*p+1][ni] = mfma16(a11, bf[ni][1], acc[2*p+1][ni]);
      }
      __builtin_amdgcn_s_setprio(0);
      if (p == 3 && tt + 1 < TOT){
        asm volatile("s_waitcnt vmcnt(0)" ::: "memory");   // issued ~3 phases ago
      }
      asm volatile("s_barrier" ::: "memory");
    }

    if (kt == NT - 1){
      int bnbase = (bng * TPW + tile) * 256;
      #pragma unroll
      for (int ni = 0; ni < 4; ++ni){
        int n = bnbase + wn*64 + ni*16 + l15;
        int dd = n >> 9, r9 = n & 511;
        int src = dd*512 + (r9 & 3)*128 + (r9 >> 2);
        float bs = bias1[src] + bias2[src];
        #pragma unroll
        for (int mi = 0; mi < 8; ++mi){
          #pragma unroll
          for (int r = 0; r < 4; ++r){
            int m = (bm << 8) + wm*128 + mi*16 + lhi*4 + r;
            C[(size_t)m * N + n] = f2bf(acc[mi][ni][r] + bs);
            acc[mi][ni][r] = 0.f;
          }
        }
      }
      ++tile; kt = 0;
    } else {
      ++kt;
    }
  }
#undef STAGE_A
#undef STAGE_B
}

// -------- persistent pipelined GEMM: BM=256, BN=192, BK=64 ----------
// MODE 1: +bias gelu bf16. MODE 2: split-K grid halves, bf16 partials to C/C2.
template<int MODE, int TPW>
__global__ __launch_bounds__(512) void k_gemmp(
    const u16* __restrict__ A, const u16* __restrict__ B,
    void* __restrict__ C, void* __restrict__ C2,
    const float* __restrict__ bias1, const float* __restrict__ bias2,
    int M, int N, int K, int lda)
{
  __shared__ __align__(16) u16 lA[2][256*64];
  __shared__ __align__(16) u16 lB[3][192*64];
  int nwg = gridDim.x;
  int bid = blockIdx.x;
  int half = 0;
  if (MODE == 2){
    int h2 = nwg >> 1;
    half = (bid >= h2) ? 1 : 0;
    bid -= half ? h2 : 0;
    nwg = h2;
  }
  int koff = half * K;
  int q = nwg >> 3;
  int swz = (bid & 7) * q + (bid >> 3);
  int nbng = N / (192 * TPW);
  int bm = swz / nbng, bng = swz % nbng;
  int tid = threadIdx.x, lane = tid & 63;
  int wv = tid >> 6;
  int wm = wv & 1, wn = wv >> 1;
  int l15 = lane & 15, lhi = lane >> 4;
  const u16* Ag = A + (size_t)(bm << 8) * lda + koff;
  const u16* Bg0 = B + (size_t)(bng * TPW) * 192 * lda + koff;
  size_t bstep = (size_t)192 * lda;

  int srA[4], slA[4];
  #pragma unroll
  for (int i = 0; i < 4; ++i){
    int c = i*512 + tid;
    srA[i] = c >> 3;
    slA[i] = (((c & 7) ^ (srA[i] & 7)) << 3);
  }
  int srB[3], slB[3];
  #pragma unroll
  for (int i = 0; i < 3; ++i){
    int c = i*512 + tid;
    srB[i] = c >> 3;
    slB[i] = (((c & 7) ^ (srB[i] & 7)) << 3);
  }
  int axr = l15 & 7;
  int aoff0 = (wm*128 + l15)*64 + ((lhi    ) ^ axr)*8;
  int aoff1 = (wm*128 + l15)*64 + ((lhi + 4) ^ axr)*8;
  int boff0 = (wn*48  + l15)*64 + ((lhi    ) ^ axr)*8;
  int boff1 = (wn*48  + l15)*64 + ((lhi + 4) ^ axr)*8;

  f32x4 acc[8][3];
  #pragma unroll
  for (int i = 0; i < 8; ++i)
    #pragma unroll
    for (int j = 0; j < 3; ++j)
      acc[i][j] = (f32x4){0.f,0.f,0.f,0.f};

  int NT = K >> 6;
  int TOT = NT * TPW;

#define STAGE_A(SS)                                                            \
  { int ss_ = (SS); int ko = (ss_ % NT) << 6; u16* dA = lA[ss_ & 1];           \
    _Pragma("unroll")                                                          \
    for (int i = 0; i < 4; ++i)                                                \
      gld_lds16(Ag + (size_t)srA[i]*lda + ko + slA[i], &dA[(i*512+tid)*8]); }
#define STAGE_B(SS)                                                            \
  { int ss_ = (SS); int ko = (ss_ % NT) << 6;                                  \
    const u16* Bb = Bg0 + (size_t)(ss_ / NT) * bstep;                          \
    u16* dB = lB[ss_ % 3];                                                     \
    _Pragma("unroll")                                                          \
    for (int i = 0; i < 3; ++i)                                                \
      gld_lds16(Bb + (size_t)srB[i]*lda + ko + slB[i], &dB[(i*512+tid)*8]); }

  STAGE_A(0)
  STAGE_B(0)
  STAGE_B(1)
  asm volatile("s_waitcnt vmcnt(3)" ::: "memory");
  __builtin_amdgcn_s_barrier();

  int kt = 0, tile = 0;
  for (int tt = 0; tt < TOT; ++tt){
    const u16* sA = lA[tt & 1];
    const u16* sB = lB[tt % 3];
    short8 bf[3][2];
    #pragma unroll
    for (int p = 0; p < 4; ++p){
      if (p == 0){
        #pragma unroll
        for (int ni = 0; ni < 3; ++ni){
          bf[ni][0] = *(const short8*)&sB[boff0 + ni*1024];
          bf[ni][1] = *(const short8*)&sB[boff1 + ni*1024];
        }
      }
      short8 a00 = *(const short8*)&sA[aoff0 + (2*p)*1024];
      short8 a01 = *(const short8*)&sA[aoff1 + (2*p)*1024];
      short8 a10 = *(const short8*)&sA[aoff0 + (2*p+1)*1024];
      short8 a11 = *(const short8*)&sA[aoff1 + (2*p+1)*1024];
      if (p == 0 && tt + 1 < TOT){ STAGE_A(tt+1) }
      if (p == 1 && tt + 2 < TOT){ STAGE_B(tt+2) }
      __builtin_amdgcn_s_setprio(1);
      #pragma unroll
      for (int ni = 0; ni < 3; ++ni){
        acc[2*p  ][ni] = mfma16(a00, bf[ni][0], acc[2*p  ][ni]);
        acc[2*p  ][ni] = mfma16(a01, bf[ni][1], acc[2*p  ][ni]);
        acc[2*p+1][ni] = mfma16(a10, bf[ni][0], acc[2*p+1][ni]);
        acc[2*p+1][ni] = mfma16(a11, bf[ni][1], acc[2*p+1][ni]);
      }
      __builtin_amdgcn_s_setprio(0);
      if (p == 3){
        if (tt + 2 < TOT){
          asm volatile("s_waitcnt vmcnt(3)" ::: "memory");
        } else if (tt + 1 < TOT){
          asm volatile("s_waitcnt vmcnt(0)" ::: "memory");
        }
      }
      asm volatile("s_barrier" ::: "memory");
    }

    if (kt == NT - 1){
      int bnbase = (bng * TPW + tile) * 192;
      #pragma unroll
      for (int ni = 0; ni < 3; ++ni){
        int n = bnbase + wn*48 + ni*16 + l15;
        float bs = bias1[n];
        #pragma unroll
        for (int mi = 0; mi < 8; ++mi){
          #pragma unroll
          for (int r = 0; r < 4; ++r){
            int m = (bm << 8) + wm*128 + mi*16 + lhi*4 + r;
            float v = acc[mi][ni][r];
            if (MODE == 2){
              if (!half) v += bs;
              ((u16*)(half ? C2 : C))[(size_t)m * N + n] = f2bf(v);
            } else {
              v += bs;
              v = 0.5f * v * (1.0f + erff(v * 0.70710678118f));
              ((u16*)C)[(size_t)m * N + n] = f2bf(v);
            }
            acc[mi][ni][r] = 0.f;
          }
        }
      }
      ++tile; kt = 0;
    } else {
      ++kt;
    }
  }
#undef STAGE_A
#undef STAGE_B
}

// ---------------- LSTM scan: 48 WGs (dir x 4 batch-groups), 512 threads ----------------
// R18: intra-wave MFMA/VALU interleave - i/f chains complete first, their sigmoids
// and ff*c product issue under the g/o MFMA chains (fills the 93%-busy-sum gap).
__global__ __launch_bounds__(512) void k_scan(const u16* __restrict__ whh, const u16* __restrict__ xp,
                       u16* __restrict__ cat)
{
  __shared__ __align__(16) u16 hb[2][4*144];   // h[batch][dim], rows padded to 144 u16
  int bid = blockIdx.x;
  int d = bid >> 2, bg = bid & 3;
  int tid = threadIdx.x, lane = tid & 63, w = tid >> 6;
  int l15 = lane & 15, lhi = lane >> 4;

  u16* hbf = (u16*)hb;
  for (int i = tid; i < 2*4*144; i += 512) hbf[i] = 0;

  short8 wf[4][4];
  #pragma unroll
  for (int g = 0; g < 4; ++g)
    #pragma unroll
    for (int kk = 0; kk < 4; ++kk)
      wf[g][kk] = *(const short8*)(whh + ((size_t)d*512 + g*128 + w*16 + l15)*128 + kk*32 + lhi*8);

  int b = bg*4 + lhi;
  int dim = w*16 + l15;
  bool fwd = (d < 6);
  const u16* zbase = xp + (size_t)b*512*6144 + d*512 + dim*4;  // + s*6144

  ushort4 Z[4];
  #pragma unroll
  for (int j = 0; j < 4; ++j){
    int s = fwd ? j : 511 - j;
    Z[j] = *(const ushort4*)(zbase + (size_t)s*6144);
  }

  f32x4 a0={0.f,0.f,0.f,0.f}, a1=a0, a2=a0, a3=a0;
  float cr = 0.f;
  int head = fwd ? d : d - 6;
  int posoff = fwd ? 0 : 128;
  size_t catlane = (size_t)b*512*1536 + head*256 + posoff + dim;
  int catoff = fwd ? 0 : 511*1536;
  int catstep = fwd ? 1536 : -1536;

  int hrd = (l15 >> 2)*144 + lhi*8;
  int hwr = lhi*144 + dim;

  __syncthreads();

#define SCAN_STEP(T, RB, WB, S)                                                \
  {                                                                            \
    short8 hf0 = *(const short8*)&hb[RB][hrd + 0*32];                          \
    short8 hf1 = *(const short8*)&hb[RB][hrd + 1*32];                          \
    short8 hf2 = *(const short8*)&hb[RB][hrd + 2*32];                          \
    short8 hf3 = *(const short8*)&hb[RB][hrd + 3*32];                          \
    a0[0] = bf2f32((u32)Z[S].x); a1[0] = bf2f32((u32)Z[S].y);                  \
    a2[0] = bf2f32((u32)Z[S].z); a3[0] = bf2f32((u32)Z[S].w);                  \
    int t4 = (T) + 4; if (t4 > 511) t4 = 511;                                  \
    int s4 = fwd ? t4 : 511 - t4;                                              \
    Z[S] = *(const ushort4*)(zbase + (size_t)s4*6144);                         \
    /* gates i,f first (chains complete early) */                              \
    a0 = mfma16(hf0, wf[0][0], a0); a1 = mfma16(hf0, wf[1][0], a1);            \
    a0 = mfma16(hf1, wf[0][1], a0); a1 = mfma16(hf1, wf[1][1], a1);            \
    a0 = mfma16(hf2, wf[0][2], a0); a1 = mfma16(hf2, wf[1][2], a1);            \
    a0 = mfma16(hf3, wf[0][3], a0); a1 = mfma16(hf3, wf[1][3], a1);            \
    /* gates g,o; i/f activations interleave under these MFMAs */              \
    a2 = mfma16(hf0, wf[2][0], a2); a3 = mfma16(hf0, wf[3][0], a3);            \
    float fi = sigf(a0[0]);                                                    \
    a2 = mfma16(hf1, wf[2][1], a2); a3 = mfma16(hf1, wf[3][1], a3);            \
    float ff = sigf(a1[0]);                                                    \
    a2 = mfma16(hf2, wf[2][2], a2); a3 = mfma16(hf2, wf[3][2], a3);            \
    float fc = ff * cr;                                                        \
    a2 = mfma16(hf3, wf[2][3], a2); a3 = mfma16(hf3, wf[3][3], a3);            \
    float tg = tanhf_(a2[0]);                                                  \
    float fo = sigf(a3[0]);                                                    \
    cr = fc + fi*tg;                                                           \
    float hv = fo * tanhf_(cr);                                                \
    u32 hp32;                                                                  \
    asm("v_cvt_pk_bf16_f32 %0, %1, %2" : "=v"(hp32) : "v"(hv), "v"(hv));       \
    u16 hp = (u16)hp32;                                                        \
    hb[WB][hwr] = hp;                                                          \
    cat[catlane + catoff] = hp;                                                \
    catoff += catstep;                                                         \
    asm volatile("s_waitcnt lgkmcnt(0)" ::: "memory");                         \
    __builtin_amdgcn_s_barrier();                                              \
  }

  for (int t = 0; t < 512; t += 4){
    SCAN_STEP(t,   0, 1, 0)
    SCAN_STEP(t+1, 1, 0, 1)
    SCAN_STEP(t+2, 0, 1, 2)
    SCAN_STEP(t+3, 1, 0, 3)
  }
#undef SCAN_STEP
}

// ---------------- residual + LayerNorm (sums two bf16 split-K partials) ----------------
__global__ __launch_bounds__(256) void k_ln(const float* __restrict__ emb, const u16* __restrict__ p0,
                     const u16* __restrict__ p1,
                     const float* __restrict__ gamma, const float* __restrict__ beta,
                     float* __restrict__ out)
{
  int row = blockIdx.x, tid = threadIdx.x;
  const float* pe = emb + (size_t)row * 768;
  const u16* pa = p0 + (size_t)row * 768;
  const u16* pb = p1 + (size_t)row * 768;
  float v0 = pe[tid]     + bf2f32(pa[tid])     + bf2f32(pb[tid]);
  float v1 = pe[tid+256] + bf2f32(pa[tid+256]) + bf2f32(pb[tid+256]);
  float v2 = pe[tid+512] + bf2f32(pa[tid+512]) + bf2f32(pb[tid+512]);
  float s = v0+v1+v2, s2 = v0*v0+v1*v1+v2*v2;
  #pragma unroll
  for (int o = 32; o > 0; o >>= 1){ s += __shfl_down(s, o); s2 += __shfl_down(s2, o); }
  __shared__ float rs[4], rq[4];
  int wv = tid >> 6;
  if ((tid & 63) == 0){ rs[wv] = s; rq[wv] = s2; }
  __syncthreads();
  s = rs[0]+rs[1]+rs[2]+rs[3];
  s2 = rq[0]+rq[1]+rq[2]+rq[3];
  float mu = s * (1.0f/768.0f);
  float var = s2 * (1.0f/768.0f) - mu*mu;
  float rr = rsqrtf(var + 1e-5f);
  float* po = out + (size_t)row * 768;
  po[tid]     = (v0-mu)*rr*gamma[tid]     + beta[tid];
  po[tid+256] = (v1-mu)*rr*gamma[tid+256] + beta[tid+256];
  po[tid+512] = (v2-mu)*rr*gamma[tid+512] + beta[tid+512];
}

extern "C" void kernel_launch(void* const* d_in, const int* in_sizes, int n_in,
                              void* d_out, int out_size, void* d_ws, size_t ws_size,
                              hipStream_t stream)
{
  const float* emb   = (const float*)d_in[0];
  const float* W_ih  = (const float*)d_in[1];
  const float* W_hh  = (const float*)d_in[2];
  const float* b_ih  = (const float*)d_in[3];
  const float* b_hh  = (const float*)d_in[4];
  const float* W_int = (const float*)d_in[5];
  const float* b_int = (const float*)d_in[6];
  const float* W_out = (const float*)d_in[7];
  const float* b_out = (const float*)d_in[8];
  const float* gamma = (const float*)d_in[9];
  const float* beta  = (const float*)d_in[10];
  float* out = (float*)d_out;

  char* ws = (char*)d_ws;
  u16* embb  = (u16*)(ws + 0);           // 12,582,912
  u16* wihb  = (u16*)(ws + 12582912);    //  9,437,184 (permuted rows)
  u16* whhb  = (u16*)(ws + 22020096);    //  1,572,864
  u16* wintb = (u16*)(ws + 23592960);    //  9,437,184
  u16* woutb = (u16*)(ws + 33030144);    //  4,718,592
  u16* catb  = (u16*)(ws + 37748736);    // 25,165,824 (dead after GEMM1)
  u16* proj1 = (u16*)(ws + 37748736);    // 12,582,912 bf16 (overlays catb)
  u16* xp    = (u16*)(ws + 62914560);    // 100,663,296 (dead after scan)
  u16* interb= (u16*)(ws + 62914560);    // 50,331,648 (reuses xp)
  u16* proj0 = (u16*)(ws + 113246208);   // 12,582,912 bf16 (reuses xp tail)

  hipLaunchKernelGGL(k_castall, dim3(13824), dim3(256), 0, stream,
                     emb, W_hh, W_int, W_out, embb, whhb, wintb, woutb);
  hipLaunchKernelGGL(k_permw, dim3(6144), dim3(192), 0, stream, W_ih, wihb);

  // x-projection: [8192,768] x [6144,768]^T -> xp row-major (gate-interleaved cols)
  hipLaunchKernelGGL((k_gemmq<3>), dim3(256), dim3(512), 0, stream,
                     embb, wihb, xp, b_ih, b_hh, 8192, 6144, 768, 768);
  // sequential BiLSTM scan -> cat [16,512,1536] bf16
  hipLaunchKernelGGL(k_scan, dim3(48), dim3(512), 0, stream, whhb, xp, catb);
  // FFN up + gelu: [8192,1536] x [3072,1536]^T -> inter bf16
  hipLaunchKernelGGL((k_gemmp<1,2>), dim3(256), dim3(512), 0, stream,
                     catb, wintb, (void*)interb, nullptr, b_int, nullptr, 8192, 3072, 1536, 1536);
  // FFN down, split-K x2: [8192,3072] x [768,3072]^T -> proj0/proj1 (bf16 partials)
  hipLaunchKernelGGL((k_gemmp<2,1>), dim3(256), dim3(512), 0, stream,
                     interb, woutb, (void*)proj0, (void*)proj1, b_out, nullptr, 8192, 768, 1536, 3072);
  // residual + LayerNorm
  hipLaunchKernelGGL(k_ln, dim3(8192), dim3(256), 0, stream, emb, proj0, proj1, gamma, beta, out);
}

// Round 19
// 481.226 us; speedup vs baseline: 1.0768x; 1.0301x over previous
//
#include <hip/hip_runtime.h>

typedef __attribute__((ext_vector_type(4))) float f32x4;
typedef __attribute__((ext_vector_type(8))) short short8;
typedef unsigned short u16;
typedef unsigned int u32;

__device__ __forceinline__ u16 f2bf(float f){
  u32 x = __float_as_uint(f);
  u32 r = x + 0x7fffu + ((x >> 16) & 1u);
  return (u16)(r >> 16);
}
__device__ __forceinline__ float bf2f32(u32 u){ return __uint_as_float(u << 16); }

__device__ __forceinline__ void gld_lds16(const u16* g, u16* l){
  __builtin_amdgcn_global_load_lds((const __attribute__((address_space(1))) void*)g,
                                   (__attribute__((address_space(3))) void*)l, 16, 0, 0);
}

__device__ __forceinline__ f32x4 mfma16(short8 a, short8 b, f32x4 c){
  return __builtin_amdgcn_mfma_f32_16x16x32_bf16(a, b, c, 0, 0, 0);
}

__device__ __forceinline__ float sigf(float x){
  return __builtin_amdgcn_rcpf(1.0f + __expf(-x));
}
__device__ __forceinline__ float tanhf_(float x){
  float e = __expf(2.0f * x);
  return 1.0f - 2.0f * __builtin_amdgcn_rcpf(e + 1.0f);
}

// ------- merged cast: emb + W_hh (flat) and W_ih (permuted) in one launch -------
__global__ __launch_bounds__(256) void k_cast2(const float* __restrict__ emb, const float* __restrict__ whh,
                        const float* __restrict__ wih,
                        u16* __restrict__ embb, u16* __restrict__ whhb, u16* __restrict__ wihb)
{
  int bid = blockIdx.x, tid = threadIdx.x;
  if (bid < 6912){
    int i = bid * 256 + tid;          // float4 index over emb(1572864) + W_hh(196608)
    const float* s; u16* d; int off;
    if (i < 1572864){ s = emb; d = embb; off = i; }
    else            { s = whh; d = whhb; off = i - 1572864; }
    float4 v = ((const float4*)s)[off];
    ushort4 o; o.x=f2bf(v.x); o.y=f2bf(v.y); o.z=f2bf(v.z); o.w=f2bf(v.w);
    ((ushort4*)d)[off] = o;
  } else if (tid < 192){
    int np = bid - 6912;              // dest row 0..6143 : n' = d*512 + dim*4 + gate
    int d = np >> 9, r = np & 511;
    int src = d*512 + (r & 3)*128 + (r >> 2);
    float4 v = ((const float4*)(wih + (size_t)src*768))[tid];
    ushort4 o; o.x=f2bf(v.x); o.y=f2bf(v.y); o.z=f2bf(v.z); o.w=f2bf(v.w);
    ((ushort4*)(wihb + (size_t)np*768))[tid] = o;
  }
}

// ---- persistent GEMM, BN=256 wave-128x64 (G0): BM=256, BK=64, TPW tiles/WG ----
template<int TPW>
__global__ __launch_bounds__(512) void k_gemmq(
    const u16* __restrict__ A, const u16* __restrict__ B,
    u16* __restrict__ C,
    const float* __restrict__ bias1, const float* __restrict__ bias2,
    int M, int N, int K, int lda)
{
  __shared__ __align__(16) u16 lA[2][256*64];
  __shared__ __align__(16) u16 lB[2][256*64];
  int nwg = gridDim.x;
  int bid = blockIdx.x;
  int q = nwg >> 3;
  int swz = (bid & 7) * q + (bid >> 3);   // XCD swizzle
  int nbng = N / (256 * TPW);
  int bm = swz / nbng, bng = swz % nbng;  // XCD chunk shares bm cohort (A in L2)
  int tid = threadIdx.x, lane = tid & 63;
  int wv = tid >> 6;
  int wm = wv & 1, wn = wv >> 1;          // wave tile: rows wm*128, cols wn*64
  int l15 = lane & 15, lhi = lane >> 4;
  const u16* Ag = A + (size_t)(bm << 8) * lda;
  const u16* Bg0 = B + (size_t)(bng * TPW) * 256 * lda;
  size_t bstep = (size_t)256 * lda;

  int srA[4], slA[4];                     // 2048 chunks of 16B (used for A and B)
  #pragma unroll
  for (int i = 0; i < 4; ++i){
    int c = i*512 + tid;
    srA[i] = c >> 3;
    slA[i] = (((c & 7) ^ (srA[i] & 7)) << 3);
  }
  int axr = l15 & 7;
  int aoff0 = (wm*128 + l15)*64 + ((lhi    ) ^ axr)*8;
  int aoff1 = (wm*128 + l15)*64 + ((lhi + 4) ^ axr)*8;
  int boff0 = (wn*64  + l15)*64 + ((lhi    ) ^ axr)*8;
  int boff1 = (wn*64  + l15)*64 + ((lhi + 4) ^ axr)*8;

  f32x4 acc[8][4];
  #pragma unroll
  for (int i = 0; i < 8; ++i)
    #pragma unroll
    for (int j = 0; j < 4; ++j)
      acc[i][j] = (f32x4){0.f,0.f,0.f,0.f};

  int NT = K >> 6;
  int TOT = NT * TPW;

#define STAGE_A(SS)                                                            \
  { int ss_ = (SS); int ko = (ss_ % NT) << 6; u16* dA = lA[ss_ & 1];           \
    _Pragma("unroll")                                                          \
    for (int i = 0; i < 4; ++i)                                                \
      gld_lds16(Ag + (size_t)srA[i]*lda + ko + slA[i], &dA[(i*512+tid)*8]); }
#define STAGE_B(SS)                                                            \
  { int ss_ = (SS); int ko = (ss_ % NT) << 6;                                  \
    const u16* Bb = Bg0 + (size_t)(ss_ / NT) * bstep;                          \
    u16* dB = lB[ss_ & 1];                                                     \
    _Pragma("unroll")                                                          \
    for (int i = 0; i < 4; ++i)                                                \
      gld_lds16(Bb + (size_t)srA[i]*lda + ko + slA[i], &dB[(i*512+tid)*8]); }

  STAGE_A(0)
  STAGE_B(0)
  asm volatile("s_waitcnt vmcnt(0)" ::: "memory");
  __builtin_amdgcn_s_barrier();

  int kt = 0, tile = 0;
  for (int tt = 0; tt < TOT; ++tt){
    const u16* sA = lA[tt & 1];
    const u16* sB = lB[tt & 1];
    short8 bf[4][2];
    #pragma unroll
    for (int p = 0; p < 4; ++p){
      if (p == 0){
        #pragma unroll
        for (int ni = 0; ni < 4; ++ni){
          bf[ni][0] = *(const short8*)&sB[boff0 + ni*1024];
          bf[ni][1] = *(const short8*)&sB[boff1 + ni*1024];
        }
      }
      short8 a00 = *(const short8*)&sA[aoff0 + (2*p)*1024];
      short8 a01 = *(const short8*)&sA[aoff1 + (2*p)*1024];
      short8 a10 = *(const short8*)&sA[aoff0 + (2*p+1)*1024];
      short8 a11 = *(const short8*)&sA[aoff1 + (2*p+1)*1024];
      if (p == 0 && tt + 1 < TOT){ STAGE_A(tt+1) }
      if (p == 1 && tt + 1 < TOT){ STAGE_B(tt+1) }
      __builtin_amdgcn_s_setprio(1);
      #pragma unroll
      for (int ni = 0; ni < 4; ++ni){
        acc[2*p  ][ni] = mfma16(a00, bf[ni][0], acc[2*p  ][ni]);
        acc[2*p  ][ni] = mfma16(a01, bf[ni][1], acc[2*p  ][ni]);
        acc[2*p+1][ni] = mfma16(a10, bf[ni][0], acc[2*p+1][ni]);
        acc[2*p+1][ni] = mfma16(a11, bf[ni][1], acc[2*p+1][ni]);
      }
      __builtin_amdgcn_s_setprio(0);
      if (p == 3 && tt + 1 < TOT){
        asm volatile("s_waitcnt vmcnt(0)" ::: "memory");   // issued ~3 phases ago
      }
      asm volatile("s_barrier" ::: "memory");
    }

    if (kt == NT - 1){
      int bnbase = (bng * TPW + tile) * 256;
      #pragma unroll
      for (int ni = 0; ni < 4; ++ni){
        int n = bnbase + wn*64 + ni*16 + l15;
        int dd = n >> 9, r9 = n & 511;
        int src = dd*512 + (r9 & 3)*128 + (r9 >> 2);
        float bs = bias1[src] + bias2[src];
        #pragma unroll
        for (int mi = 0; mi < 8; ++mi){
          #pragma unroll
          for (int r = 0; r < 4; ++r){
            int m = (bm << 8) + wm*128 + mi*16 + lhi*4 + r;
            C[(size_t)m * N + n] = f2bf(acc[mi][ni][r] + bs);
            acc[mi][ni][r] = 0.f;
          }
        }
      }
      ++tile; kt = 0;
    } else {
      ++kt;
    }
  }
#undef STAGE_A
#undef STAGE_B
}

// -------- persistent pipelined GEMM: BM=256, BN=192, BK=64 ----------
// MODE 1: +bias gelu bf16. MODE 2: split-K grid halves, bf16 partials to C/C2.
template<int MODE, int TPW>
__global__ __launch_bounds__(512) void k_gemmp(
    const u16* __restrict__ A, const u16* __restrict__ B,
    void* __restrict__ C, void* __restrict__ C2,
    const float* __restrict__ bias1, const float* __restrict__ bias2,
    int M, int N, int K, int lda)
{
  __shared__ __align__(16) u16 lA[2][256*64];
  __shared__ __align__(16) u16 lB[3][192*64];
  int nwg = gridDim.x;
  int bid = blockIdx.x;
  int half = 0;
  if (MODE == 2){
    int h2 = nwg >> 1;
    half = (bid >= h2) ? 1 : 0;
    bid -= half ? h2 : 0;
    nwg = h2;
  }
  int koff = half * K;
  int q = nwg >> 3;
  int swz = (bid & 7) * q + (bid >> 3);
  int nbng = N / (192 * TPW);
  int bm = swz / nbng, bng = swz % nbng;
  int tid = threadIdx.x, lane = tid & 63;
  int wv = tid >> 6;
  int wm = wv & 1, wn = wv >> 1;
  int l15 = lane & 15, lhi = lane >> 4;
  const u16* Ag = A + (size_t)(bm << 8) * lda + koff;
  const u16* Bg0 = B + (size_t)(bng * TPW) * 192 * lda + koff;
  size_t bstep = (size_t)192 * lda;

  int srA[4], slA[4];
  #pragma unroll
  for (int i = 0; i < 4; ++i){
    int c = i*512 + tid;
    srA[i] = c >> 3;
    slA[i] = (((c & 7) ^ (srA[i] & 7)) << 3);
  }
  int srB[3], slB[3];
  #pragma unroll
  for (int i = 0; i < 3; ++i){
    int c = i*512 + tid;
    srB[i] = c >> 3;
    slB[i] = (((c & 7) ^ (srB[i] & 7)) << 3);
  }
  int axr = l15 & 7;
  int aoff0 = (wm*128 + l15)*64 + ((lhi    ) ^ axr)*8;
  int aoff1 = (wm*128 + l15)*64 + ((lhi + 4) ^ axr)*8;
  int boff0 = (wn*48  + l15)*64 + ((lhi    ) ^ axr)*8;
  int boff1 = (wn*48  + l15)*64 + ((lhi + 4) ^ axr)*8;

  f32x4 acc[8][3];
  #pragma unroll
  for (int i = 0; i < 8; ++i)
    #pragma unroll
    for (int j = 0; j < 3; ++j)
      acc[i][j] = (f32x4){0.f,0.f,0.f,0.f};

  int NT = K >> 6;
  int TOT = NT * TPW;

#define STAGE_A(SS)                                                            \
  { int ss_ = (SS); int ko = (ss_ % NT) << 6; u16* dA = lA[ss_ & 1];           \
    _Pragma("unroll")                                                          \
    for (int i = 0; i < 4; ++i)                                                \
      gld_lds16(Ag + (size_t)srA[i]*lda + ko + slA[i], &dA[(i*512+tid)*8]); }
#define STAGE_B(SS)                                                            \
  { int ss_ = (SS); int ko = (ss_ % NT) << 6;                                  \
    const u16* Bb = Bg0 + (size_t)(ss_ / NT) * bstep;                          \
    u16* dB = lB[ss_ % 3];                                                     \
    _Pragma("unroll")                                                          \
    for (int i = 0; i < 3; ++i)                                                \
      gld_lds16(Bb + (size_t)srB[i]*lda + ko + slB[i], &dB[(i*512+tid)*8]); }

  STAGE_A(0)
  STAGE_B(0)
  STAGE_B(1)
  asm volatile("s_waitcnt vmcnt(3)" ::: "memory");
  __builtin_amdgcn_s_barrier();

  int kt = 0, tile = 0;
  for (int tt = 0; tt < TOT; ++tt){
    const u16* sA = lA[tt & 1];
    const u16* sB = lB[tt % 3];
    short8 bf[3][2];
    #pragma unroll
    for (int p = 0; p < 4; ++p){
      if (p == 0){
        #pragma unroll
        for (int ni = 0; ni < 3; ++ni){
          bf[ni][0] = *(const short8*)&sB[boff0 + ni*1024];
          bf[ni][1] = *(const short8*)&sB[boff1 + ni*1024];
        }
      }
      short8 a00 = *(const short8*)&sA[aoff0 + (2*p)*1024];
      short8 a01 = *(const short8*)&sA[aoff1 + (2*p)*1024];
      short8 a10 = *(const short8*)&sA[aoff0 + (2*p+1)*1024];
      short8 a11 = *(const short8*)&sA[aoff1 + (2*p+1)*1024];
      if (p == 0 && tt + 1 < TOT){ STAGE_A(tt+1) }
      if (p == 1 && tt + 2 < TOT){ STAGE_B(tt+2) }
      __builtin_amdgcn_s_setprio(1);
      #pragma unroll
      for (int ni = 0; ni < 3; ++ni){
        acc[2*p  ][ni] = mfma16(a00, bf[ni][0], acc[2*p  ][ni]);
        acc[2*p  ][ni] = mfma16(a01, bf[ni][1], acc[2*p  ][ni]);
        acc[2*p+1][ni] = mfma16(a10, bf[ni][0], acc[2*p+1][ni]);
        acc[2*p+1][ni] = mfma16(a11, bf[ni][1], acc[2*p+1][ni]);
      }
      __builtin_amdgcn_s_setprio(0);
      if (p == 3){
        if (tt + 2 < TOT){
          asm volatile("s_waitcnt vmcnt(3)" ::: "memory");
        } else if (tt + 1 < TOT){
          asm volatile("s_waitcnt vmcnt(0)" ::: "memory");
        }
      }
      asm volatile("s_barrier" ::: "memory");
    }

    if (kt == NT - 1){
      int bnbase = (bng * TPW + tile) * 192;
      #pragma unroll
      for (int ni = 0; ni < 3; ++ni){
        int n = bnbase + wn*48 + ni*16 + l15;
        float bs = bias1[n];
        #pragma unroll
        for (int mi = 0; mi < 8; ++mi){
          #pragma unroll
          for (int r = 0; r < 4; ++r){
            int m = (bm << 8) + wm*128 + mi*16 + lhi*4 + r;
            float v = acc[mi][ni][r];
            if (MODE == 2){
              if (!half) v += bs;
              ((u16*)(half ? C2 : C))[(size_t)m * N + n] = f2bf(v);
            } else {
              v += bs;
              v = 0.5f * v * (1.0f + erff(v * 0.70710678118f));
              ((u16*)C)[(size_t)m * N + n] = f2bf(v);
            }
            acc[mi][ni][r] = 0.f;
          }
        }
      }
      ++tile; kt = 0;
    } else {
      ++kt;
    }
  }
#undef STAGE_A
#undef STAGE_B
}

// ---------------- LSTM scan (WG 0-47) + W_int/W_out cast (WG 48-255) ----------------
// 96KB dummy LDS forces 1 WG/CU: cast WGs never share a CU with scan WGs.
// Scan: R17 MFMA order (gate-g first), rolling prefetch pointer, clamp-free main
// loop (steps 0-507) + no-prefetch tail (508-511).
__global__ __launch_bounds__(512) void k_scan(const u16* __restrict__ whh, const u16* __restrict__ xp,
                       u16* __restrict__ cat,
                       const float* __restrict__ wint, const float* __restrict__ wout,
                       u16* __restrict__ wintb, u16* __restrict__ woutb)
{
  __shared__ __align__(16) u16 big[49152];   // 96KB; scan uses first 2x576
  int bid = blockIdx.x;
  int tid = threadIdx.x;

  if (bid >= 48){
    // cast role: W_int (1179648 f4) + W_out (589824 f4) over 208 WGs x 512 thr
    for (int i = (bid - 48)*512 + tid; i < 1769472; i += 208*512){
      const float* s; u16* d; int off;
      if (i < 1179648){ s = wint; d = wintb; off = i; }
      else            { s = wout; d = woutb; off = i - 1179648; }
      float4 v = ((const float4*)s)[off];
      ushort4 o; o.x=f2bf(v.x); o.y=f2bf(v.y); o.z=f2bf(v.z); o.w=f2bf(v.w);
      ((ushort4*)d)[off] = o;
    }
    return;
  }

  u16* hb = big;                             // hb[RB*576 + x]
  int d = bid >> 2, bg = bid & 3;
  int lane = tid & 63, w = tid >> 6;
  int l15 = lane & 15, lhi = lane >> 4;

  for (int i = tid; i < 2*576; i += 512) hb[i] = 0;

  short8 wf[4][4];
  #pragma unroll
  for (int g = 0; g < 4; ++g)
    #pragma unroll
    for (int kk = 0; kk < 4; ++kk)
      wf[g][kk] = *(const short8*)(whh + ((size_t)d*512 + g*128 + w*16 + l15)*128 + kk*32 + lhi*8);

  int b = bg*4 + lhi;
  int dim = w*16 + l15;
  bool fwd = (d < 6);
  const u16* zbase = xp + (size_t)b*512*6144 + d*512 + dim*4;  // + s*6144

  ushort4 Z[4];
  #pragma unroll
  for (int j = 0; j < 4; ++j){
    int s = fwd ? j : 511 - j;
    Z[j] = *(const ushort4*)(zbase + (size_t)s*6144);
  }
  // rolling prefetch pointer: step 4's slice, advancing +-6144 u16 per step
  const u16* zpre = zbase + (size_t)(fwd ? 4 : 507) * 6144;
  int zstep = fwd ? 6144 : -6144;

  f32x4 a0={0.f,0.f,0.f,0.f}, a1=a0, a2=a0, a3=a0;
  float cr = 0.f;
  int head = fwd ? d : d - 6;
  int posoff = fwd ? 0 : 128;
  size_t catlane = (size_t)b*512*1536 + head*256 + posoff + dim;
  int catoff = fwd ? 0 : 511*1536;
  int catstep = fwd ? 1536 : -1536;

  int hrd = (l15 >> 2)*144 + lhi*8;
  int hwr = lhi*144 + dim;

  __syncthreads();

#define SCAN_BODY(RB, WB, S, PRE)                                              \
  {                                                                            \
    short8 hf0 = *(const short8*)&hb[(RB)*576 + hrd + 0*32];                   \
    short8 hf1 = *(const short8*)&hb[(RB)*576 + hrd + 1*32];                   \
    short8 hf2 = *(const short8*)&hb[(RB)*576 + hrd + 2*32];                   \
    short8 hf3 = *(const short8*)&hb[(RB)*576 + hrd + 3*32];                   \
    a0[0] = bf2f32((u32)Z[S].x); a1[0] = bf2f32((u32)Z[S].y);                  \
    a2[0] = bf2f32((u32)Z[S].z); a3[0] = bf2f32((u32)Z[S].w);                  \
    if (PRE){ Z[S] = *(const ushort4*)zpre; zpre += zstep; }                   \
    a2 = mfma16(hf0, wf[2][0], a2); a0 = mfma16(hf0, wf[0][0], a0);            \
    a1 = mfma16(hf0, wf[1][0], a1); a3 = mfma16(hf0, wf[3][0], a3);            \
    a2 = mfma16(hf1, wf[2][1], a2); a0 = mfma16(hf1, wf[0][1], a0);            \
    a1 = mfma16(hf1, wf[1][1], a1); a3 = mfma16(hf1, wf[3][1], a3);            \
    a2 = mfma16(hf2, wf[2][2], a2); a0 = mfma16(hf2, wf[0][2], a0);            \
    a1 = mfma16(hf2, wf[1][2], a1); a3 = mfma16(hf2, wf[3][2], a3);            \
    a2 = mfma16(hf3, wf[2][3], a2); a0 = mfma16(hf3, wf[0][3], a0);            \
    a1 = mfma16(hf3, wf[1][3], a1); a3 = mfma16(hf3, wf[3][3], a3);            \
    float tg = tanhf_(a2[0]);                                                  \
    float fi = sigf(a0[0]), ff = sigf(a1[0]), fo = sigf(a3[0]);                \
    cr = ff*cr + fi*tg;                                                        \
    float hv = fo * tanhf_(cr);                                                \
    u32 hp32;                                                                  \
    asm("v_cvt_pk_bf16_f32 %0, %1, %2" : "=v"(hp32) : "v"(hv), "v"(hv));       \
    u16 hp = (u16)hp32;                                                        \
    hb[(WB)*576 + hwr] = hp;                                                   \
    cat[catlane + catoff] = hp;                                                \
    catoff += catstep;                                                         \
    asm volatile("s_waitcnt lgkmcnt(0)" ::: "memory");                         \
    __builtin_amdgcn_s_barrier();                                              \
  }

  for (int t = 0; t < 508; t += 4){
    SCAN_BODY(0, 1, 0, 1)
    SCAN_BODY(1, 0, 1, 1)
    SCAN_BODY(0, 1, 2, 1)
    SCAN_BODY(1, 0, 3, 1)
  }
  // tail: steps 508-511, no prefetch
  SCAN_BODY(0, 1, 0, 0)
  SCAN_BODY(1, 0, 1, 0)
  SCAN_BODY(0, 1, 2, 0)
  SCAN_BODY(1, 0, 3, 0)
#undef SCAN_BODY
}

// ---------------- residual + LayerNorm (sums two bf16 split-K partials) ----------------
__global__ __launch_bounds__(256) void k_ln(const float* __restrict__ emb, const u16* __restrict__ p0,
                     const u16* __restrict__ p1,
                     const float* __restrict__ gamma, const float* __restrict__ beta,
                     float* __restrict__ out)
{
  int row = blockIdx.x, tid = threadIdx.x;
  const float* pe = emb + (size_t)row * 768;
  const u16* pa = p0 + (size_t)row * 768;
  const u16* pb = p1 + (size_t)row * 768;
  float v0 = pe[tid]     + bf2f32(pa[tid])     + bf2f32(pb[tid]);
  float v1 = pe[tid+256] + bf2f32(pa[tid+256]) + bf2f32(pb[tid+256]);
  float v2 = pe[tid+512] + bf2f32(pa[tid+512]) + bf2f32(pb[tid+512]);
  float s = v0+v1+v2, s2 = v0*v0+v1*v1+v2*v2;
  #pragma unroll
  for (int o = 32; o > 0; o >>= 1){ s += __shfl_down(s, o); s2 += __shfl_down(s2, o); }
  __shared__ float rs[4], rq[4];
  int wv = tid >> 6;
  if ((tid & 63) == 0){ rs[wv] = s; rq[wv] = s2; }
  __syncthreads();
  s = rs[0]+rs[1]+rs[2]+rs[3];
  s2 = rq[0]+rq[1]+rq[2]+rq[3];
  float mu = s * (1.0f/768.0f);
  float var = s2 * (1.0f/768.0f) - mu*mu;
  float rr = rsqrtf(var + 1e-5f);
  float* po = out + (size_t)row * 768;
  po[tid]     = (v0-mu)*rr*gamma[tid]     + beta[tid];
  po[tid+256] = (v1-mu)*rr*gamma[tid+256] + beta[tid+256];
  po[tid+512] = (v2-mu)*rr*gamma[tid+512] + beta[tid+512];
}

extern "C" void kernel_launch(void* const* d_in, const int* in_sizes, int n_in,
                              void* d_out, int out_size, void* d_ws, size_t ws_size,
                              hipStream_t stream)
{
  const float* emb   = (const float*)d_in[0];
  const float* W_ih  = (const float*)d_in[1];
  const float* W_hh  = (const float*)d_in[2];
  const float* b_ih  = (const float*)d_in[3];
  const float* b_hh  = (const float*)d_in[4];
  const float* W_int = (const float*)d_in[5];
  const float* b_int = (const float*)d_in[6];
  const float* W_out = (const float*)d_in[7];
  const float* b_out = (const float*)d_in[8];
  const float* gamma = (const float*)d_in[9];
  const float* beta  = (const float*)d_in[10];
  float* out = (float*)d_out;

  char* ws = (char*)d_ws;
  u16* embb  = (u16*)(ws + 0);           // 12,582,912
  u16* wihb  = (u16*)(ws + 12582912);    //  9,437,184 (permuted rows)
  u16* whhb  = (u16*)(ws + 22020096);    //  1,572,864
  u16* wintb = (u16*)(ws + 23592960);    //  9,437,184
  u16* woutb = (u16*)(ws + 33030144);    //  4,718,592
  u16* catb  = (u16*)(ws + 37748736);    // 25,165,824 (dead after GEMM1)
  u16* proj1 = (u16*)(ws + 37748736);    // 12,582,912 bf16 (overlays catb)
  u16* xp    = (u16*)(ws + 62914560);    // 100,663,296 (dead after scan)
  u16* interb= (u16*)(ws + 62914560);    // 50,331,648 (reuses xp)
  u16* proj0 = (u16*)(ws + 113246208);   // 12,582,912 bf16 (reuses xp tail)

  // emb + W_hh cast, W_ih permute-cast (one launch)
  hipLaunchKernelGGL(k_cast2, dim3(13056), dim3(256), 0, stream,
                     emb, W_hh, W_ih, embb, whhb, wihb);

  // x-projection: [8192,768] x [6144,768]^T -> xp row-major (gate-interleaved cols)
  hipLaunchKernelGGL((k_gemmq<3>), dim3(256), dim3(512), 0, stream,
                     embb, wihb, xp, b_ih, b_hh, 8192, 6144, 768, 768);
  // sequential BiLSTM scan (48 WGs) + W_int/W_out cast on idle CUs (208 WGs)
  hipLaunchKernelGGL(k_scan, dim3(256), dim3(512), 0, stream,
                     whhb, xp, catb, W_int, W_out, wintb, woutb);
  // FFN up + gelu: [8192,1536] x [3072,1536]^T -> inter bf16
  hipLaunchKernelGGL((k_gemmp<1,2>), dim3(256), dim3(512), 0, stream,
                     catb, wintb, (void*)interb, nullptr, b_int, nullptr, 8192, 3072, 1536, 1536);
  // FFN down, split-K x2: [8192,3072] x [768,3072]^T -> proj0/proj1 (bf16 partials)
  hipLaunchKernelGGL((k_gemmp<2,1>), dim3(256), dim3(512), 0, stream,
                     interb, woutb, (void*)proj0, (void*)proj1, b_out, nullptr, 8192, 768, 1536, 3072);
  // residual + LayerNorm
  hipLaunchKernelGGL(k_ln, dim3(8192), dim3(256), 0, stream, emb, proj0, proj1, gamma, beta, out);
}

// Round 20
// 481.070 us; speedup vs baseline: 1.0772x; 1.0003x over previous
//
#include <hip/hip_runtime.h>

typedef __attribute__((ext_vector_type(4))) float f32x4;
typedef __attribute__((ext_vector_type(8))) short short8;
typedef unsigned short u16;
typedef unsigned int u32;

__device__ __forceinline__ u16 f2bf(float f){
  u32 x = __float_as_uint(f);
  u32 r = x + 0x7fffu + ((x >> 16) & 1u);
  return (u16)(r >> 16);
}
__device__ __forceinline__ float bf2f32(u32 u){ return __uint_as_float(u << 16); }

__device__ __forceinline__ void gld_lds16(const u16* g, u16* l){
  __builtin_amdgcn_global_load_lds((const __attribute__((address_space(1))) void*)g,
                                   (__attribute__((address_space(3))) void*)l, 16, 0, 0);
}

__device__ __forceinline__ f32x4 mfma16(short8 a, short8 b, f32x4 c){
  return __builtin_amdgcn_mfma_f32_16x16x32_bf16(a, b, c, 0, 0, 0);
}

__device__ __forceinline__ float sigf(float x){
  return __builtin_amdgcn_rcpf(1.0f + __expf(-x));
}
__device__ __forceinline__ float tanhf_(float x){
  float e = __expf(2.0f * x);
  return 1.0f - 2.0f * __builtin_amdgcn_rcpf(e + 1.0f);
}

// ------- merged cast: emb + W_hh (flat) and W_ih (permuted) in one launch -------
__global__ __launch_bounds__(256) void k_cast2(const float* __restrict__ emb, const float* __restrict__ whh,
                        const float* __restrict__ wih,
                        u16* __restrict__ embb, u16* __restrict__ whhb, u16* __restrict__ wihb)
{
  int bid = blockIdx.x, tid = threadIdx.x;
  if (bid < 6912){
    int i = bid * 256 + tid;          // float4 index over emb(1572864) + W_hh(196608)
    const float* s; u16* d; int off;
    if (i < 1572864){ s = emb; d = embb; off = i; }
    else            { s = whh; d = whhb; off = i - 1572864; }
    float4 v = ((const float4*)s)[off];
    ushort4 o; o.x=f2bf(v.x); o.y=f2bf(v.y); o.z=f2bf(v.z); o.w=f2bf(v.w);
    ((ushort4*)d)[off] = o;
  } else if (tid < 192){
    int np = bid - 6912;              // dest row 0..6143 : n' = d*512 + dim*4 + gate
    int d = np >> 9, r = np & 511;
    int src = d*512 + (r & 3)*128 + (r >> 2);
    float4 v = ((const float4*)(wih + (size_t)src*768))[tid];
    ushort4 o; o.x=f2bf(v.x); o.y=f2bf(v.y); o.z=f2bf(v.z); o.w=f2bf(v.w);
    ((ushort4*)(wihb + (size_t)np*768))[tid] = o;
  }
}

// ---- persistent GEMM, BN=256 wave-128x64 (G0): BM=256, BK=64, TPW tiles/WG ----
template<int TPW>
__global__ __launch_bounds__(512) void k_gemmq(
    const u16* __restrict__ A, const u16* __restrict__ B,
    u16* __restrict__ C,
    const float* __restrict__ bias1, const float* __restrict__ bias2,
    int M, int N, int K, int lda)
{
  __shared__ __align__(16) u16 lA[2][256*64];
  __shared__ __align__(16) u16 lB[2][256*64];
  int nwg = gridDim.x;
  int bid = blockIdx.x;
  int q = nwg >> 3;
  int swz = (bid & 7) * q + (bid >> 3);   // XCD swizzle
  int nbng = N / (256 * TPW);
  int bm = swz / nbng, bng = swz % nbng;  // XCD chunk shares bm cohort (A in L2)
  int tid = threadIdx.x, lane = tid & 63;
  int wv = tid >> 6;
  int wm = wv & 1, wn = wv >> 1;          // wave tile: rows wm*128, cols wn*64
  int l15 = lane & 15, lhi = lane >> 4;
  const u16* Ag = A + (size_t)(bm << 8) * lda;
  const u16* Bg0 = B + (size_t)(bng * TPW) * 256 * lda;
  size_t bstep = (size_t)256 * lda;

  int srA[4], slA[4];                     // 2048 chunks of 16B (used for A and B)
  #pragma unroll
  for (int i = 0; i < 4; ++i){
    int c = i*512 + tid;
    srA[i] = c >> 3;
    slA[i] = (((c & 7) ^ (srA[i] & 7)) << 3);
  }
  int axr = l15 & 7;
  int aoff0 = (wm*128 + l15)*64 + ((lhi    ) ^ axr)*8;
  int aoff1 = (wm*128 + l15)*64 + ((lhi + 4) ^ axr)*8;
  int boff0 = (wn*64  + l15)*64 + ((lhi    ) ^ axr)*8;
  int boff1 = (wn*64  + l15)*64 + ((lhi + 4) ^ axr)*8;

  f32x4 acc[8][4];
  #pragma unroll
  for (int i = 0; i < 8; ++i)
    #pragma unroll
    for (int j = 0; j < 4; ++j)
      acc[i][j] = (f32x4){0.f,0.f,0.f,0.f};

  int NT = K >> 6;
  int TOT = NT * TPW;

#define STAGE_A(SS)                                                            \
  { int ss_ = (SS); int ko = (ss_ % NT) << 6; u16* dA = lA[ss_ & 1];           \
    _Pragma("unroll")                                                          \
    for (int i = 0; i < 4; ++i)                                                \
      gld_lds16(Ag + (size_t)srA[i]*lda + ko + slA[i], &dA[(i*512+tid)*8]); }
#define STAGE_B(SS)                                                            \
  { int ss_ = (SS); int ko = (ss_ % NT) << 6;                                  \
    const u16* Bb = Bg0 + (size_t)(ss_ / NT) * bstep;                          \
    u16* dB = lB[ss_ & 1];                                                     \
    _Pragma("unroll")                                                          \
    for (int i = 0; i < 4; ++i)                                                \
      gld_lds16(Bb + (size_t)srA[i]*lda + ko + slA[i], &dB[(i*512+tid)*8]); }

  STAGE_A(0)
  STAGE_B(0)
  asm volatile("s_waitcnt vmcnt(0)" ::: "memory");
  __builtin_amdgcn_s_barrier();

  int kt = 0, tile = 0;
  for (int tt = 0; tt < TOT; ++tt){
    const u16* sA = lA[tt & 1];
    const u16* sB = lB[tt & 1];
    short8 bf[4][2];
    #pragma unroll
    for (int p = 0; p < 4; ++p){
      if (p == 0){
        #pragma unroll
        for (int ni = 0; ni < 4; ++ni){
          bf[ni][0] = *(const short8*)&sB[boff0 + ni*1024];
          bf[ni][1] = *(const short8*)&sB[boff1 + ni*1024];
        }
      }
      short8 a00 = *(const short8*)&sA[aoff0 + (2*p)*1024];
      short8 a01 = *(const short8*)&sA[aoff1 + (2*p)*1024];
      short8 a10 = *(const short8*)&sA[aoff0 + (2*p+1)*1024];
      short8 a11 = *(const short8*)&sA[aoff1 + (2*p+1)*1024];
      if (p == 0 && tt + 1 < TOT){ STAGE_A(tt+1) }
      if (p == 1 && tt + 1 < TOT){ STAGE_B(tt+1) }
      __builtin_amdgcn_s_setprio(1);
      #pragma unroll
      for (int ni = 0; ni < 4; ++ni){
        acc[2*p  ][ni] = mfma16(a00, bf[ni][0], acc[2*p  ][ni]);
        acc[2*p  ][ni] = mfma16(a01, bf[ni][1], acc[2*p  ][ni]);
        acc[2*p+1][ni] = mfma16(a10, bf[ni][0], acc[2*p+1][ni]);
        acc[2*p+1][ni] = mfma16(a11, bf[ni][1], acc[2*p+1][ni]);
      }
      __builtin_amdgcn_s_setprio(0);
      if (p == 3 && tt + 1 < TOT){
        asm volatile("s_waitcnt vmcnt(0)" ::: "memory");   // issued ~3 phases ago
      }
      asm volatile("s_barrier" ::: "memory");
    }

    if (kt == NT - 1){
      int bnbase = (bng * TPW + tile) * 256;
      #pragma unroll
      for (int ni = 0; ni < 4; ++ni){
        int n = bnbase + wn*64 + ni*16 + l15;
        int dd = n >> 9, r9 = n & 511;
        int src = dd*512 + (r9 & 3)*128 + (r9 >> 2);
        float bs = bias1[src] + bias2[src];
        #pragma unroll
        for (int mi = 0; mi < 8; ++mi){
          #pragma unroll
          for (int r = 0; r < 4; ++r){
            int m = (bm << 8) + wm*128 + mi*16 + lhi*4 + r;
            C[(size_t)m * N + n] = f2bf(acc[mi][ni][r] + bs);
            acc[mi][ni][r] = 0.f;
          }
        }
      }
      ++tile; kt = 0;
    } else {
      ++kt;
    }
  }
#undef STAGE_A
#undef STAGE_B
}

// -------- persistent pipelined GEMM: BM=256, BN=192, BK=64 ----------
// MODE 1: +bias gelu bf16. MODE 2: split-K grid halves, bf16 partials to C/C2.
template<int MODE, int TPW>
__global__ __launch_bounds__(512) void k_gemmp(
    const u16* __restrict__ A, const u16* __restrict__ B,
    void* __restrict__ C, void* __restrict__ C2,
    const float* __restrict__ bias1, const float* __restrict__ bias2,
    int M, int N, int K, int lda)
{
  __shared__ __align__(16) u16 lA[2][256*64];
  __shared__ __align__(16) u16 lB[3][192*64];
  int nwg = gridDim.x;
  int bid = blockIdx.x;
  int half = 0;
  if (MODE == 2){
    int h2 = nwg >> 1;
    half = (bid >= h2) ? 1 : 0;
    bid -= half ? h2 : 0;
    nwg = h2;
  }
  int koff = half * K;
  int q = nwg >> 3;
  int swz = (bid & 7) * q + (bid >> 3);
  int nbng = N / (192 * TPW);
  int bm = swz / nbng, bng = swz % nbng;
  int tid = threadIdx.x, lane = tid & 63;
  int wv = tid >> 6;
  int wm = wv & 1, wn = wv >> 1;
  int l15 = lane & 15, lhi = lane >> 4;
  const u16* Ag = A + (size_t)(bm << 8) * lda + koff;
  const u16* Bg0 = B + (size_t)(bng * TPW) * 192 * lda + koff;
  size_t bstep = (size_t)192 * lda;

  int srA[4], slA[4];
  #pragma unroll
  for (int i = 0; i < 4; ++i){
    int c = i*512 + tid;
    srA[i] = c >> 3;
    slA[i] = (((c & 7) ^ (srA[i] & 7)) << 3);
  }
  int srB[3], slB[3];
  #pragma unroll
  for (int i = 0; i < 3; ++i){
    int c = i*512 + tid;
    srB[i] = c >> 3;
    slB[i] = (((c & 7) ^ (srB[i] & 7)) << 3);
  }
  int axr = l15 & 7;
  int aoff0 = (wm*128 + l15)*64 + ((lhi    ) ^ axr)*8;
  int aoff1 = (wm*128 + l15)*64 + ((lhi + 4) ^ axr)*8;
  int boff0 = (wn*48  + l15)*64 + ((lhi    ) ^ axr)*8;
  int boff1 = (wn*48  + l15)*64 + ((lhi + 4) ^ axr)*8;

  f32x4 acc[8][3];
  #pragma unroll
  for (int i = 0; i < 8; ++i)
    #pragma unroll
    for (int j = 0; j < 3; ++j)
      acc[i][j] = (f32x4){0.f,0.f,0.f,0.f};

  int NT = K >> 6;
  int TOT = NT * TPW;

#define STAGE_A(SS)                                                            \
  { int ss_ = (SS); int ko = (ss_ % NT) << 6; u16* dA = lA[ss_ & 1];           \
    _Pragma("unroll")                                                          \
    for (int i = 0; i < 4; ++i)                                                \
      gld_lds16(Ag + (size_t)srA[i]*lda + ko + slA[i], &dA[(i*512+tid)*8]); }
#define STAGE_B(SS)                                                            \
  { int ss_ = (SS); int ko = (ss_ % NT) << 6;                                  \
    const u16* Bb = Bg0 + (size_t)(ss_ / NT) * bstep;                          \
    u16* dB = lB[ss_ % 3];                                                     \
    _Pragma("unroll")                                                          \
    for (int i = 0; i < 3; ++i)                                                \
      gld_lds16(Bb + (size_t)srB[i]*lda + ko + slB[i], &dB[(i*512+tid)*8]); }

  STAGE_A(0)
  STAGE_B(0)
  STAGE_B(1)
  asm volatile("s_waitcnt vmcnt(3)" ::: "memory");
  __builtin_amdgcn_s_barrier();

  int kt = 0, tile = 0;
  for (int tt = 0; tt < TOT; ++tt){
    const u16* sA = lA[tt & 1];
    const u16* sB = lB[tt % 3];
    short8 bf[3][2];
    #pragma unroll
    for (int p = 0; p < 4; ++p){
      if (p == 0){
        #pragma unroll
        for (int ni = 0; ni < 3; ++ni){
          bf[ni][0] = *(const short8*)&sB[boff0 + ni*1024];
          bf[ni][1] = *(const short8*)&sB[boff1 + ni*1024];
        }
      }
      short8 a00 = *(const short8*)&sA[aoff0 + (2*p)*1024];
      short8 a01 = *(const short8*)&sA[aoff1 + (2*p)*1024];
      short8 a10 = *(const short8*)&sA[aoff0 + (2*p+1)*1024];
      short8 a11 = *(const short8*)&sA[aoff1 + (2*p+1)*1024];
      if (p == 0 && tt + 1 < TOT){ STAGE_A(tt+1) }
      if (p == 1 && tt + 2 < TOT){ STAGE_B(tt+2) }
      __builtin_amdgcn_s_setprio(1);
      #pragma unroll
      for (int ni = 0; ni < 3; ++ni){
        acc[2*p  ][ni] = mfma16(a00, bf[ni][0], acc[2*p  ][ni]);
        acc[2*p  ][ni] = mfma16(a01, bf[ni][1], acc[2*p  ][ni]);
        acc[2*p+1][ni] = mfma16(a10, bf[ni][0], acc[2*p+1][ni]);
        acc[2*p+1][ni] = mfma16(a11, bf[ni][1], acc[2*p+1][ni]);
      }
      __builtin_amdgcn_s_setprio(0);
      if (p == 3){
        if (tt + 2 < TOT){
          asm volatile("s_waitcnt vmcnt(3)" ::: "memory");
        } else if (tt + 1 < TOT){
          asm volatile("s_waitcnt vmcnt(0)" ::: "memory");
        }
      }
      asm volatile("s_barrier" ::: "memory");
    }

    if (kt == NT - 1){
      int bnbase = (bng * TPW + tile) * 192;
      #pragma unroll
      for (int ni = 0; ni < 3; ++ni){
        int n = bnbase + wn*48 + ni*16 + l15;
        float bs = bias1[n];
        #pragma unroll
        for (int mi = 0; mi < 8; ++mi){
          #pragma unroll
          for (int r = 0; r < 4; ++r){
            int m = (bm << 8) + wm*128 + mi*16 + lhi*4 + r;
            float v = acc[mi][ni][r];
            if (MODE == 2){
              if (!half) v += bs;
              ((u16*)(half ? C2 : C))[(size_t)m * N + n] = f2bf(v);
            } else {
              v += bs;
              v = 0.5f * v * (1.0f + erff(v * 0.70710678118f));
              ((u16*)C)[(size_t)m * N + n] = f2bf(v);
            }
            acc[mi][ni][r] = 0.f;
          }
        }
      }
      ++tile; kt = 0;
    } else {
      ++kt;
    }
  }
#undef STAGE_A
#undef STAGE_B
}

// ---------------- LSTM scan (WG 0-47) + W_int/W_out cast (WG 48-255) ----------------
__global__ __launch_bounds__(512) void k_scan(const u16* __restrict__ whh, const u16* __restrict__ xp,
                       u16* __restrict__ cat,
                       const float* __restrict__ wint, const float* __restrict__ wout,
                       u16* __restrict__ wintb, u16* __restrict__ woutb)
{
  __shared__ __align__(16) u16 big[49152];   // 96KB; scan uses first 2x576
  int bid = blockIdx.x;
  int tid = threadIdx.x;

  if (bid >= 48){
    for (int i = (bid - 48)*512 + tid; i < 1769472; i += 208*512){
      const float* s; u16* d; int off;
      if (i < 1179648){ s = wint; d = wintb; off = i; }
      else            { s = wout; d = woutb; off = i - 1179648; }
      float4 v = ((const float4*)s)[off];
      ushort4 o; o.x=f2bf(v.x); o.y=f2bf(v.y); o.z=f2bf(v.z); o.w=f2bf(v.w);
      ((ushort4*)d)[off] = o;
    }
    return;
  }

  u16* hb = big;                             // hb[RB*576 + x]
  int d = bid >> 2, bg = bid & 3;
  int lane = tid & 63, w = tid >> 6;
  int l15 = lane & 15, lhi = lane >> 4;

  for (int i = tid; i < 2*576; i += 512) hb[i] = 0;

  short8 wf[4][4];
  #pragma unroll
  for (int g = 0; g < 4; ++g)
    #pragma unroll
    for (int kk = 0; kk < 4; ++kk)
      wf[g][kk] = *(const short8*)(whh + ((size_t)d*512 + g*128 + w*16 + l15)*128 + kk*32 + lhi*8);

  int b = bg*4 + lhi;
  int dim = w*16 + l15;
  bool fwd = (d < 6);
  const u16* zbase = xp + (size_t)b*512*6144 + d*512 + dim*4;  // + s*6144

  ushort4 Z[4];
  #pragma unroll
  for (int j = 0; j < 4; ++j){
    int s = fwd ? j : 511 - j;
    Z[j] = *(const ushort4*)(zbase + (size_t)s*6144);
  }
  const u16* zpre = zbase + (size_t)(fwd ? 4 : 507) * 6144;
  int zstep = fwd ? 6144 : -6144;

  f32x4 a0={0.f,0.f,0.f,0.f}, a1=a0, a2=a0, a3=a0;
  float cr = 0.f;
  int head = fwd ? d : d - 6;
  int posoff = fwd ? 0 : 128;
  size_t catlane = (size_t)b*512*1536 + head*256 + posoff + dim;
  int catoff = fwd ? 0 : 511*1536;
  int catstep = fwd ? 1536 : -1536;

  int hrd = (l15 >> 2)*144 + lhi*8;
  int hwr = lhi*144 + dim;

  __syncthreads();

#define SCAN_BODY(RB, WB, S, PRE)                                              \
  {                                                                            \
    short8 hf0 = *(const short8*)&hb[(RB)*576 + hrd + 0*32];                   \
    short8 hf1 = *(const short8*)&hb[(RB)*576 + hrd + 1*32];                   \
    short8 hf2 = *(const short8*)&hb[(RB)*576 + hrd + 2*32];                   \
    short8 hf3 = *(const short8*)&hb[(RB)*576 + hrd + 3*32];                   \
    a0[0] = bf2f32((u32)Z[S].x); a1[0] = bf2f32((u32)Z[S].y);                  \
    a2[0] = bf2f32((u32)Z[S].z); a3[0] = bf2f32((u32)Z[S].w);                  \
    if (PRE){ Z[S] = *(const ushort4*)zpre; zpre += zstep; }                   \
    a2 = mfma16(hf0, wf[2][0], a2); a0 = mfma16(hf0, wf[0][0], a0);            \
    a1 = mfma16(hf0, wf[1][0], a1); a3 = mfma16(hf0, wf[3][0], a3);            \
    a2 = mfma16(hf1, wf[2][1], a2); a0 = mfma16(hf1, wf[0][1], a0);            \
    a1 = mfma16(hf1, wf[1][1], a1); a3 = mfma16(hf1, wf[3][1], a3);            \
    a2 = mfma16(hf2, wf[2][2], a2); a0 = mfma16(hf2, wf[0][2], a0);            \
    a1 = mfma16(hf2, wf[1][2], a1); a3 = mfma16(hf2, wf[3][2], a3);            \
    a2 = mfma16(hf3, wf[2][3], a2); a0 = mfma16(hf3, wf[0][3], a0);            \
    a1 = mfma16(hf3, wf[1][3], a1); a3 = mfma16(hf3, wf[3][3], a3);            \
    float tg = tanhf_(a2[0]);                                                  \
    float fi = sigf(a0[0]), ff = sigf(a1[0]), fo = sigf(a3[0]);                \
    cr = ff*cr + fi*tg;                                                        \
    float hv = fo * tanhf_(cr);                                                \
    u32 hp32;                                                                  \
    asm("v_cvt_pk_bf16_f32 %0, %1, %2" : "=v"(hp32) : "v"(hv), "v"(hv));       \
    u16 hp = (u16)hp32;                                                        \
    hb[(WB)*576 + hwr] = hp;                                                   \
    cat[catlane + catoff] = hp;                                                \
    catoff += catstep;                                                         \
    asm volatile("s_waitcnt lgkmcnt(0)" ::: "memory");                         \
    __builtin_amdgcn_s_barrier();                                              \
  }

  for (int t = 0; t < 508; t += 4){
    SCAN_BODY(0, 1, 0, 1)
    SCAN_BODY(1, 0, 1, 1)
    SCAN_BODY(0, 1, 2, 1)
    SCAN_BODY(1, 0, 3, 1)
  }
  SCAN_BODY(0, 1, 0, 0)
  SCAN_BODY(1, 0, 1, 0)
  SCAN_BODY(0, 1, 2, 0)
  SCAN_BODY(1, 0, 3, 0)
#undef SCAN_BODY
}

// ------- residual + LayerNorm: wave-per-row, fully vectorized, no LDS -------
__global__ __launch_bounds__(256) void k_ln(const float* __restrict__ emb, const u16* __restrict__ p0,
                     const u16* __restrict__ p1,
                     const float* __restrict__ gamma, const float* __restrict__ beta,
                     float* __restrict__ out)
{
  int tid = threadIdx.x;
  int w = tid >> 6, l = tid & 63;
  int row = blockIdx.x * 4 + w;
  const float* pe = emb + (size_t)row * 768;
  const u16* pa = p0 + (size_t)row * 768;
  const u16* pb = p1 + (size_t)row * 768;

  float v[12];
  #pragma unroll
  for (int k = 0; k < 3; ++k){
    float4 e = ((const float4*)pe)[l + k*64];
    ushort4 a4 = ((const ushort4*)pa)[l + k*64];
    ushort4 b4 = ((const ushort4*)pb)[l + k*64];
    v[4*k+0] = e.x + bf2f32(a4.x) + bf2f32(b4.x);
    v[4*k+1] = e.y + bf2f32(a4.y) + bf2f32(b4.y);
    v[4*k+2] = e.z + bf2f32(a4.z) + bf2f32(b4.z);
    v[4*k+3] = e.w + bf2f32(a4.w) + bf2f32(b4.w);
  }
  float s = 0.f, s2 = 0.f;
  #pragma unroll
  for (int j = 0; j < 12; ++j){ s += v[j]; s2 += v[j]*v[j]; }
  #pragma unroll
  for (int o = 32; o > 0; o >>= 1){ s += __shfl_down(s, o); s2 += __shfl_down(s2, o); }
  s = __shfl(s, 0); s2 = __shfl(s2, 0);
  float mu = s * (1.0f/768.0f);
  float var = s2 * (1.0f/768.0f) - mu*mu;
  float rr = rsqrtf(var + 1e-5f);
  float* po = out + (size_t)row * 768;
  #pragma unroll
  for (int k = 0; k < 3; ++k){
    float4 g4 = ((const float4*)gamma)[l + k*64];
    float4 be = ((const float4*)beta)[l + k*64];
    float4 o4;
    o4.x = (v[4*k+0]-mu)*rr*g4.x + be.x;
    o4.y = (v[4*k+1]-mu)*rr*g4.y + be.y;
    o4.z = (v[4*k+2]-mu)*rr*g4.z + be.z;
    o4.w = (v[4*k+3]-mu)*rr*g4.w + be.w;
    ((float4*)po)[l + k*64] = o4;
  }
}

extern "C" void kernel_launch(void* const* d_in, const int* in_sizes, int n_in,
                              void* d_out, int out_size, void* d_ws, size_t ws_size,
                              hipStream_t stream)
{
  const float* emb   = (const float*)d_in[0];
  const float* W_ih  = (const float*)d_in[1];
  const float* W_hh  = (const float*)d_in[2];
  const float* b_ih  = (const float*)d_in[3];
  const float* b_hh  = (const float*)d_in[4];
  const float* W_int = (const float*)d_in[5];
  const float* b_int = (const float*)d_in[6];
  const float* W_out = (const float*)d_in[7];
  const float* b_out = (const float*)d_in[8];
  const float* gamma = (const float*)d_in[9];
  const float* beta  = (const float*)d_in[10];
  float* out = (float*)d_out;

  char* ws = (char*)d_ws;
  u16* embb  = (u16*)(ws + 0);           // 12,582,912
  u16* wihb  = (u16*)(ws + 12582912);    //  9,437,184 (permuted rows)
  u16* whhb  = (u16*)(ws + 22020096);    //  1,572,864
  u16* wintb = (u16*)(ws + 23592960);    //  9,437,184
  u16* woutb = (u16*)(ws + 33030144);    //  4,718,592
  u16* catb  = (u16*)(ws + 37748736);    // 25,165,824 (dead after GEMM1)
  u16* proj1 = (u16*)(ws + 37748736);    // 12,582,912 bf16 (overlays catb)
  u16* xp    = (u16*)(ws + 62914560);    // 100,663,296 (dead after scan)
  u16* interb= (u16*)(ws + 62914560);    // 50,331,648 (reuses xp)
  u16* proj0 = (u16*)(ws + 113246208);   // 12,582,912 bf16 (reuses xp tail)

  // emb + W_hh cast, W_ih permute-cast (one launch)
  hipLaunchKernelGGL(k_cast2, dim3(13056), dim3(256), 0, stream,
                     emb, W_hh, W_ih, embb, whhb, wihb);

  // x-projection: [8192,768] x [6144,768]^T -> xp row-major (gate-interleaved cols)
  hipLaunchKernelGGL((k_gemmq<3>), dim3(256), dim3(512), 0, stream,
                     embb, wihb, xp, b_ih, b_hh, 8192, 6144, 768, 768);
  // sequential BiLSTM scan (48 WGs) + W_int/W_out cast on idle CUs (208 WGs)
  hipLaunchKernelGGL(k_scan, dim3(256), dim3(512), 0, stream,
                     whhb, xp, catb, W_int, W_out, wintb, woutb);
  // FFN up + gelu: [8192,1536] x [3072,1536]^T -> inter bf16
  hipLaunchKernelGGL((k_gemmp<1,2>), dim3(256), dim3(512), 0, stream,
                     catb, wintb, (void*)interb, nullptr, b_int, nullptr, 8192, 3072, 1536, 1536);
  // FFN down, split-K x2: [8192,3072] x [768,3072]^T -> proj0/proj1 (bf16 partials)
  hipLaunchKernelGGL((k_gemmp<2,1>), dim3(256), dim3(512), 0, stream,
                     interb, woutb, (void*)proj0, (void*)proj1, b_out, nullptr, 8192, 768, 1536, 3072);
  // residual + LayerNorm (wave-per-row)
  hipLaunchKernelGGL(k_ln, dim3(2048), dim3(256), 0, stream, emb, proj0, proj1, gamma, beta, out);
}